// Round 12
// baseline (3836.171 us; speedup 1.0000x reference)
//
#include <hip/hip_runtime.h>
#include <cstddef>

// Problem constants
#define Bsz  4096
#define Sseq 16
#define Gdim 128
#define Edim 256
#define Hdim 512
#define H4   2048
#define Psteps 16
#define BK   16

typedef short bfrag8 __attribute__((ext_vector_type(8)));   // 8 bf16 (4 VGPR)
typedef float f32x4  __attribute__((ext_vector_type(4)));   // MFMA acc

// Exact 3-way bf16 split of fp32 (truncation; residuals exactly representable:
// 24 mantissa bits = 8+8+8). a == hi+mid+lo exactly (normal range).
__device__ __forceinline__ void split3(float f, unsigned short& h,
                                       unsigned short& m, unsigned short& l) {
    unsigned u = __float_as_uint(f);
    h = (unsigned short)(u >> 16);
    float r1 = f - __uint_as_float(u & 0xffff0000u);
    unsigned u1 = __float_as_uint(r1);
    m = (unsigned short)(u1 >> 16);
    float r2 = r1 - __uint_as_float(u1 & 0xffff0000u);
    l = (unsigned short)(__float_as_uint(r2) >> 16);
}

// ---------------------------------------------------------------------------
// Fold kernel: gate-interleaved (row c = j*4+gate) weight prep, emitting
// bf16 hi/mid/lo planes for the MFMA path. Wih rows staged in LDS first
// (coalesced), e-loop reads LDS broadcasts -- same sequential FMA order.
// ---------------------------------------------------------------------------
__global__ void fold_kernel(const float* __restrict__ encWih,
                            const float* __restrict__ encWhh,
                            const float* __restrict__ enc_b,
                            const float* __restrict__ decWih,
                            const float* __restrict__ decWhh,
                            const float* __restrict__ dec_b,
                            const float* __restrict__ embW,
                            const float* __restrict__ dec0,
                            unsigned short* __restrict__ encEh,
                            unsigned short* __restrict__ encEm,
                            unsigned short* __restrict__ encEl,
                            unsigned short* __restrict__ encWh,
                            unsigned short* __restrict__ encWm,
                            unsigned short* __restrict__ encWl,
                            unsigned short* __restrict__ decEh,
                            unsigned short* __restrict__ decEm,
                            unsigned short* __restrict__ decEl,
                            unsigned short* __restrict__ decWh,
                            unsigned short* __restrict__ decWm,
                            unsigned short* __restrict__ decWl,
                            float* __restrict__ encBI, float* __restrict__ decBI,
                            float* __restrict__ v0bI) {
    __shared__ float rE[Edim], rD[Edim];
    const int o = blockIdx.x;            // original row 0..2047 (gate*512 + j)
    const int gate = o >> 9, j = o & 511;
    const int c = j * 4 + gate;          // interleaved row
    const int g = threadIdx.x;           // 0..127
    rE[g]        = encWih[(size_t)o * Edim + g];
    rE[g + Gdim] = encWih[(size_t)o * Edim + g + Gdim];
    rD[g]        = decWih[(size_t)o * Edim + g];
    rD[g + Gdim] = decWih[(size_t)o * Edim + g + Gdim];
    __syncthreads();

    float se = 0.f, sd = 0.f;
#pragma unroll 8
    for (int e = 0; e < Edim; ++e) {
        float w = embW[e * Gdim + g];
        se += rE[e] * w;                 // same sequential order as before
        sd += rD[e] * w;
    }
    unsigned short h, m, l;
    split3(se, h, m, l);
    encEh[(size_t)c * Gdim + g] = h; encEm[(size_t)c * Gdim + g] = m;
    encEl[(size_t)c * Gdim + g] = l;
    split3(sd, h, m, l);
    decEh[(size_t)c * Gdim + g] = h; decEm[(size_t)c * Gdim + g] = m;
    decEl[(size_t)c * Gdim + g] = l;
    for (int k = g; k < Hdim; k += Gdim) {
        split3(encWhh[(size_t)o * Hdim + k], h, m, l);
        encWh[(size_t)c * Hdim + k] = h; encWm[(size_t)c * Hdim + k] = m;
        encWl[(size_t)c * Hdim + k] = l;
        split3(decWhh[(size_t)o * Hdim + k], h, m, l);
        decWh[(size_t)c * Hdim + k] = h; decWm[(size_t)c * Hdim + k] = m;
        decWl[(size_t)c * Hdim + k] = l;
    }
    if (g == 0) {
        encBI[c] = enc_b[o];
        decBI[c] = dec_b[o];
        float s = dec_b[o];
        for (int e = 0; e < Edim; ++e) s += rD[e] * dec0[e];  // same order
        v0bI[c] = s;
    }
}

// ---------------------------------------------------------------------------
// Plane prep for the projection weights (Wref2, Wq2): row-major hi/mid/lo
// bf16 planes, 512x512 each. grid (512, 2).
// ---------------------------------------------------------------------------
__global__ __launch_bounds__(256) void fold_proj(
    const float* __restrict__ Wr, const float* __restrict__ Wq,
    unsigned short* __restrict__ rWh, unsigned short* __restrict__ rWm,
    unsigned short* __restrict__ rWl,
    unsigned short* __restrict__ qWh, unsigned short* __restrict__ qWm,
    unsigned short* __restrict__ qWl) {
    const int o = blockIdx.x;
    const float* src = blockIdx.y ? Wq : Wr;
    unsigned short* ph = blockIdx.y ? qWh : rWh;
    unsigned short* pm = blockIdx.y ? qWm : rWm;
    unsigned short* pl = blockIdx.y ? qWl : rWl;
    for (int k = threadIdx.x; k < Hdim; k += 256) {
        unsigned short h, m, l;
        split3(src[(size_t)o * Hdim + k], h, m, l);
        ph[(size_t)o * Hdim + k] = h;
        pm[(size_t)o * Hdim + k] = m;
        pl[(size_t)o * Hdim + k] = l;
    }
}

// ---------------------------------------------------------------------------
// MFMA gates GEMM + fused LSTM epilogue, fp32-exact via bf16x6 emulation.
// Round-12: occupancy via grid, everything else held. 2 waves/SIMD was the
// binder (grid 512 x 80KB LDS -> 2 blocks/CU; VGPR 92 allowed 5). Changes:
//  (a) act-LDS staging dropped -- its DEDUP purpose became moot with the
//      round-10 wave->m-slice remap (each act fragment now read by exactly
//      one wave); acts load direct per-lane float4 (bit-identical values).
//      LDS falls to 48 KB -> 3 blocks/CU fit.
//  (b) block m halved to 64 (wave = 16m x all-128n, acc 8x1); grid (64,16)
//      = 1024 blocks -> ~3 resident blocks/CU = 12 waves/CU = 3 waves/SIMD.
//      n-panel stays 128 (round-7's act-redundancy mistake avoided); total
//      split3 work chip-wide unchanged.
// Weight staging machinery, swizzles, chunk order, 6-MFMA order verbatim ->
// output bit-identical.
// ---------------------------------------------------------------------------
__global__ __launch_bounds__(256) void gates_mfma(
    const unsigned short* __restrict__ Wh1, const unsigned short* __restrict__ Wm1,
    const unsigned short* __restrict__ Wl1, int K1,
    const float* __restrict__ X, int ldx,
    const int* __restrict__ gather, int gmul,
    const unsigned short* __restrict__ Wh2, const unsigned short* __restrict__ Wm2,
    const unsigned short* __restrict__ Wl2, int K2,
    const float* __restrict__ Hin,
    const float* __restrict__ biasI,
    const float* __restrict__ c_in, float* __restrict__ h_out,
    float* __restrict__ c_out, int czero)
{
    __shared__ __align__(16) unsigned short wlds[2][3 * 4096]; // 48 KB

    const int tid = threadIdx.x;
    const int wv = tid >> 6, lane = tid & 63;
    const int lm = lane & 15, quad = lane >> 4;
    const int c0 = blockIdx.y * 128;             // block n-panel base row
    const int mB0 = blockIdx.x * 64;             // block batch base (64 rows)

    const int mrow = mB0 + wv * 16 + lm;         // this lane's act/output row

    // ---- weight staging geometry (unchanged): 128 rows x 32k x 3 planes ----
    int srow[2], sqs[2];
#pragma unroll
    for (int i = 0; i < 2; ++i) {
        const int seg = i * 4 + wv;
        const int r = seg * 16 + (lane >> 2);
        srow[i] = r;
        sqs[i] = (lane & 3) ^ ((r >> 1) & 3);    // pre-swizzled source chunk
    }
    size_t roff1[2], roff2[2];
#pragma unroll
    for (int i = 0; i < 2; ++i) {
        roff1[i] = (size_t)(c0 + srow[i]) * K1 + (size_t)(sqs[i] * 8);
        roff2[i] = (size_t)(c0 + srow[i]) * K2 + (size_t)(sqs[i] * 8);
    }

    // ---- act pointers (direct global; remap means no intra-block dup) ----
    const float* xr = nullptr;
    const float* hr = nullptr;
    if (X) {
        size_t off = (size_t)mrow * ldx;
        if (gather) off += (size_t)gather[mrow] * gmul;
        xr = X + off;
    }
    if (Hin) hr = Hin + (size_t)mrow * K2;

    // ---- weight ds_read fragment offsets (ushort units), 8 n-tiles ----
    int boffW[8];
#pragma unroll
    for (int tn = 0; tn < 8; ++tn) {
        const int r = tn * 16 + lm;
        boffW[tn] = r * 32 + ((quad ^ ((r >> 1) & 3)) * 8);
    }

    auto stage = [&](int kcN, int buf) {
        const bool nX = kcN < K1;
        const int kb = nX ? kcN : kcN - K1;
#pragma unroll
        for (int i = 0; i < 2; ++i) {
            const int seg = i * 4 + wv;
            unsigned short* lb = &wlds[buf][seg * 512];
            const unsigned short* gh = (nX ? Wh1 + roff1[i] : Wh2 + roff2[i]) + kb;
            const unsigned short* gm = (nX ? Wm1 + roff1[i] : Wm2 + roff2[i]) + kb;
            const unsigned short* gl = (nX ? Wl1 + roff1[i] : Wl2 + roff2[i]) + kb;
            __builtin_amdgcn_global_load_lds(
                (const __attribute__((address_space(1))) void*)gh,
                (__attribute__((address_space(3))) void*)(lb), 16, 0, 0);
            __builtin_amdgcn_global_load_lds(
                (const __attribute__((address_space(1))) void*)gm,
                (__attribute__((address_space(3))) void*)(lb + 4096), 16, 0, 0);
            __builtin_amdgcn_global_load_lds(
                (const __attribute__((address_space(1))) void*)gl,
                (__attribute__((address_space(3))) void*)(lb + 8192), 16, 0, 0);
        }
    };

    f32x4 acc[8];
#pragma unroll
    for (int i = 0; i < 8; ++i) acc[i] = (f32x4){0.f, 0.f, 0.f, 0.f};

    const int KT = K1 + K2;
    stage(0, 0);
    int cur = 0;

    for (int kc = 0; kc < KT; kc += 32) {
        __syncthreads();                       // drains staged loads for buf[cur]
        if (kc + 32 < KT) stage(kc + 32, cur ^ 1);

        const bool inX = kc < K1;
        const int kk = (inX ? kc : kc - K1) + quad * 8;

        // this wave's single act fragment: direct global, split3 in VALU
        const float* p = (inX ? xr : hr) + kk;
        float a8[8];
        *(float4*)&a8[0] = *(const float4*)(p);
        *(float4*)&a8[4] = *(const float4*)(p + 4);
        bfrag8 bh, bm, bl;
#pragma unroll
        for (int j = 0; j < 8; ++j) {
            unsigned short h, m, l;
            split3(a8[j], h, m, l);
            bh[j] = (short)h; bm[j] = (short)m; bl[j] = (short)l;
        }

        const unsigned short* bufp = wlds[cur];
#pragma unroll
        for (int hh = 0; hh < 2; ++hh) {
            bfrag8 ah[4], am4[4], al[4];
#pragma unroll
            for (int t = 0; t < 4; ++t) {
                const int tn = hh * 4 + t;
                ah[t]  = *(const bfrag8*)(bufp + boffW[tn]);
                am4[t] = *(const bfrag8*)(bufp + 4096 + boffW[tn]);
                al[t]  = *(const bfrag8*)(bufp + 8192 + boffW[tn]);
            }
#pragma unroll
            for (int t = 0; t < 4; ++t) {
                const int tn = hh * 4 + t;
                f32x4 c = acc[tn];
                c = __builtin_amdgcn_mfma_f32_16x16x32_bf16(ah[t], bl, c, 0, 0, 0);
                c = __builtin_amdgcn_mfma_f32_16x16x32_bf16(al[t], bh, c, 0, 0, 0);
                c = __builtin_amdgcn_mfma_f32_16x16x32_bf16(am4[t], bm, c, 0, 0, 0);
                c = __builtin_amdgcn_mfma_f32_16x16x32_bf16(ah[t], bm, c, 0, 0, 0);
                c = __builtin_amdgcn_mfma_f32_16x16x32_bf16(am4[t], bh, c, 0, 0, 0);
                c = __builtin_amdgcn_mfma_f32_16x16x32_bf16(ah[t], bh, c, 0, 0, 0);
                acc[tn] = c;
            }
        }
        cur ^= 1;
    }

    // fused LSTM epilogue: lane's 4 acc regs = gates i,f,g,o of unit j
#pragma unroll
    for (int tn = 0; tn < 8; ++tn) {
        const int nb = c0 + tn * 16 + quad * 4;
        float4 bb = *(const float4*)(biasI + nb);
        const int j = nb >> 2;
        const size_t idx = (size_t)mrow * Hdim + j;
        float gi = acc[tn][0] + bb.x;
        float gf = acc[tn][1] + bb.y;
        float gg = acc[tn][2] + bb.z;
        float go = acc[tn][3] + bb.w;
        float si = 1.f / (1.f + expf(-gi));
        float sf = 1.f / (1.f + expf(-gf));
        float so = 1.f / (1.f + expf(-go));
        float co = czero ? 0.f : c_in[idx];
        float cn = si * tanhf(gg) + sf * co;
        c_out[idx] = cn;
        h_out[idx] = so * tanhf(cn);
    }
}

// ---------------------------------------------------------------------------
// MFMA projection GEMM: C = A @ W^T + bias (A 4096x512 fp32, W via bf16x6
// planes, K=512). Same bf16x6 scheme as gates (identical 6-term order).
// 64m x 64n block, 4 waves (wave = 16m x 64n, acc 4x1), grid (64,8)=512,
// dual LDS double-buffer staging with the proven both-sides swizzles.
// ---------------------------------------------------------------------------
__global__ __launch_bounds__(256) void proj_mfma(
    const unsigned short* __restrict__ Wh, const unsigned short* __restrict__ Wm,
    const unsigned short* __restrict__ Wl,
    const float* __restrict__ A,
    const float* __restrict__ bias,
    float* __restrict__ C, int ldc)
{
    __shared__ __align__(16) unsigned short wlds[2][3 * 2048]; // 24 KB
    __shared__ __align__(16) float alds[2][64 * 32];           // 16 KB

    const int tid = threadIdx.x;
    const int wv = tid >> 6, lane = tid & 63;
    const int lm = lane & 15, quad = lane >> 4;
    const int nB0 = blockIdx.y * 64;             // output-channel panel base
    const int mB0 = blockIdx.x * 64;             // batch tile base

    // ---- weight staging: 64 rows x 4 x 16B units, 256 threads, 1 issue ----
    const int rw = tid >> 2;                               // row 0..63
    const int sqw = (tid & 3) ^ ((rw >> 1) & 3);           // swizzled src unit
    const size_t wroff = (size_t)(nB0 + rw) * Hdim + (size_t)(sqw * 8);

    // ---- act staging: 2 issues x 32 rows x 8 x 16B units ----
    const int asw = ((lane & 7) ^ (lane >> 3)) * 4;        // swizzled src floats
    const float* asrc[2];
#pragma unroll
    for (int i = 0; i < 2; ++i) {
        const int r = i * 32 + wv * 8 + (lane >> 3);
        asrc[i] = A + (size_t)(mB0 + r) * Hdim + asw;
    }

    // ---- ds_read offsets ----
    int boffW[4];
#pragma unroll
    for (int tn = 0; tn < 4; ++tn) {
        const int r = tn * 16 + lm;
        boffW[tn] = r * 32 + ((quad ^ ((r >> 1) & 3)) * 8);
    }
    const int ra = wv * 16 + lm;                           // wave's act row
    const int boffA1 = ra * 32 + (((2 * quad)     ^ (lm & 7)) << 2);
    const int boffA2 = ra * 32 + (((2 * quad + 1) ^ (lm & 7)) << 2);

    auto stage = [&](int kb, int buf) {
        unsigned short* lb0 = &wlds[buf][wv * 512];
        __builtin_amdgcn_global_load_lds(
            (const __attribute__((address_space(1))) void*)(Wh + wroff + kb),
            (__attribute__((address_space(3))) void*)(lb0), 16, 0, 0);
        __builtin_amdgcn_global_load_lds(
            (const __attribute__((address_space(1))) void*)(Wm + wroff + kb),
            (__attribute__((address_space(3))) void*)(lb0 + 2048), 16, 0, 0);
        __builtin_amdgcn_global_load_lds(
            (const __attribute__((address_space(1))) void*)(Wl + wroff + kb),
            (__attribute__((address_space(3))) void*)(lb0 + 4096), 16, 0, 0);
#pragma unroll
        for (int i = 0; i < 2; ++i) {
            float* lb = &alds[buf][(i * 32 + wv * 8) * 32];
            __builtin_amdgcn_global_load_lds(
                (const __attribute__((address_space(1))) void*)(asrc[i] + kb),
                (__attribute__((address_space(3))) void*)lb, 16, 0, 0);
        }
    };

    f32x4 acc[4];
#pragma unroll
    for (int i = 0; i < 4; ++i) acc[i] = (f32x4){0.f, 0.f, 0.f, 0.f};

    stage(0, 0);
    int cur = 0;

    for (int kc = 0; kc < Hdim; kc += 32) {
        __syncthreads();
        if (kc + 32 < Hdim) stage(kc + 32, cur ^ 1);

        const float* abuf = alds[cur];
        float a8[8];
        *(float4*)&a8[0] = *(const float4*)(abuf + boffA1);
        *(float4*)&a8[4] = *(const float4*)(abuf + boffA2);
        bfrag8 bh, bm, bl;
#pragma unroll
        for (int j = 0; j < 8; ++j) {
            unsigned short h, m, l;
            split3(a8[j], h, m, l);
            bh[j] = (short)h; bm[j] = (short)m; bl[j] = (short)l;
        }

        const unsigned short* bufp = wlds[cur];
#pragma unroll
        for (int tn = 0; tn < 4; ++tn) {
            bfrag8 ah  = *(const bfrag8*)(bufp + boffW[tn]);
            bfrag8 am4 = *(const bfrag8*)(bufp + 2048 + boffW[tn]);
            bfrag8 al  = *(const bfrag8*)(bufp + 4096 + boffW[tn]);
            f32x4 c = acc[tn];
            c = __builtin_amdgcn_mfma_f32_16x16x32_bf16(ah,  bl, c, 0, 0, 0);
            c = __builtin_amdgcn_mfma_f32_16x16x32_bf16(al,  bh, c, 0, 0, 0);
            c = __builtin_amdgcn_mfma_f32_16x16x32_bf16(am4, bm, c, 0, 0, 0);
            c = __builtin_amdgcn_mfma_f32_16x16x32_bf16(ah,  bm, c, 0, 0, 0);
            c = __builtin_amdgcn_mfma_f32_16x16x32_bf16(am4, bh, c, 0, 0, 0);
            c = __builtin_amdgcn_mfma_f32_16x16x32_bf16(ah,  bh, c, 0, 0, 0);
            acc[tn] = c;
        }
        cur ^= 1;
    }

    // epilogue: lane reg r of acc[tn] = channel nB0+tn*16+quad*4+r, batch
    // row mB0+wv*16+lm (planes NOT gate-interleaved).
    const int m = mB0 + wv * 16 + lm;
#pragma unroll
    for (int tn = 0; tn < 4; ++tn) {
        const int n = nB0 + tn * 16 + quad * 4;
        float4 bb = *(const float4*)(bias + n);
        float4 o;
        o.x = acc[tn][0] + bb.x;
        o.y = acc[tn][1] + bb.y;
        o.z = acc[tn][2] + bb.z;
        o.w = acc[tn][3] + bb.w;
        *(float4*)(C + (size_t)m * ldc + n) = o;
    }
}

// ---------------------------------------------------------------------------
// Attention + log-softmax + argmax + state update.
// ---------------------------------------------------------------------------
__global__ __launch_bounds__(256) void attn_step(const float* __restrict__ qp,
                                                 const float* __restrict__ u2,
                                                 const float* __restrict__ Vec2,
                                                 float* __restrict__ mask,
                                                 float* __restrict__ ll_ws,
                                                 int* __restrict__ nxt,
                                                 float* __restrict__ out_map,
                                                 float* __restrict__ out_ll,
                                                 int step, int node) {
    const int b = blockIdx.x;
    __shared__ float qpS[Hdim];
    __shared__ float vS[Hdim];
    __shared__ float logitS[Sseq];
    const int tid = threadIdx.x;
    qpS[tid]       = qp[(size_t)b * Hdim + tid];
    qpS[tid + 256] = qp[(size_t)b * Hdim + 256 + tid];
    vS[tid]        = Vec2[tid];
    vS[tid + 256]  = Vec2[256 + tid];
    __syncthreads();

    const int wave = tid >> 6, lane = tid & 63;
    for (int si = 0; si < 4; ++si) {
        int s = wave * 4 + si;
        const float* u2p = u2 + ((size_t)b * Sseq + s) * Hdim;
        float sum = 0.f;
#pragma unroll
        for (int i = 0; i < 8; ++i) {
            int hh = lane + i * 64;
            sum += vS[hh] * tanhf(qpS[hh] + u2p[hh]);
        }
        for (int off = 32; off > 0; off >>= 1) sum += __shfl_down(sum, off);
        if (lane == 0) {
            float pen = step ? mask[b * Sseq + s] * 1e8f : 0.f;
            logitS[s] = 10.f * sum - pen;
        }
    }
    __syncthreads();

    if (tid == 0) {
        float mx = logitS[0];
        int am = 0;
        for (int s = 1; s < Sseq; ++s)
            if (logitS[s] > mx) { mx = logitS[s]; am = s; }
        float se = 0.f;
        for (int s = 0; s < Sseq; ++s) se += expf(logitS[s] - mx);
        float lp = -logf(se);
        float llv = (step ? ll_ws[b] : 0.f) + lp;
        ll_ws[b] = llv;
        out_ll[b] = llv;
        nxt[b] = am;
        if (step == 0) {
            for (int s = 0; s < Sseq; ++s) mask[b * Sseq + s] = (s == am) ? 1.f : 0.f;
        } else {
            mask[b * Sseq + am] += 1.f;
        }
        out_map[b * Sseq + am] = (float)node;
    }
}

// ---------------------------------------------------------------------------
extern "C" void kernel_launch(void* const* d_in, const int* in_sizes, int n_in,
                              void* d_out, int out_size, void* d_ws, size_t ws_size,
                              hipStream_t stream) {
    const float* x       = (const float*)d_in[0];
    const float* emb_W   = (const float*)d_in[1];
    const float* enc_Wih = (const float*)d_in[2];
    const float* enc_Whh = (const float*)d_in[3];
    const float* enc_b   = (const float*)d_in[4];
    const float* dec_Wih = (const float*)d_in[5];
    const float* dec_Whh = (const float*)d_in[6];
    const float* dec_b   = (const float*)d_in[7];
    const float* Wq2     = (const float*)d_in[8];
    const float* bq2     = (const float*)d_in[9];
    const float* Wref2   = (const float*)d_in[10];
    const float* bref2   = (const float*)d_in[11];
    const float* Vec2    = (const float*)d_in[12];
    const float* dec0    = (const float*)d_in[13];

    // workspace layout — ~195 MB
    float* ws      = (float*)d_ws;
    float* u2      = ws;                                   // B*S*H fp32
    float* h0      = u2 + (size_t)Bsz * Sseq * Hdim;       // B*H each
    float* c0      = h0 + (size_t)Bsz * Hdim;
    float* h1      = c0 + (size_t)Bsz * Hdim;
    float* c1      = h1 + (size_t)Bsz * Hdim;
    float* qp      = c1 + (size_t)Bsz * Hdim;
    float* mask    = qp + (size_t)Bsz * Hdim;              // B*S
    float* ll      = mask + (size_t)Bsz * Sseq;            // B
    int*   nxt     = (int*)(ll + Bsz);                     // B
    float* encBI   = (float*)(nxt + Bsz);                  // 2048 each
    float* decBI   = encBI + H4;
    float* v0bI    = decBI + H4;
    // bf16 weight planes (ushort)
    unsigned short* us = (unsigned short*)(v0bI + H4);
    unsigned short* encEh = us;                       us += (size_t)H4 * Gdim;
    unsigned short* encEm = us;                       us += (size_t)H4 * Gdim;
    unsigned short* encEl = us;                       us += (size_t)H4 * Gdim;
    unsigned short* encWh = us;                       us += (size_t)H4 * Hdim;
    unsigned short* encWm = us;                       us += (size_t)H4 * Hdim;
    unsigned short* encWl = us;                       us += (size_t)H4 * Hdim;
    unsigned short* decEh = us;                       us += (size_t)H4 * Gdim;
    unsigned short* decEm = us;                       us += (size_t)H4 * Gdim;
    unsigned short* decEl = us;                       us += (size_t)H4 * Gdim;
    unsigned short* decWh = us;                       us += (size_t)H4 * Hdim;
    unsigned short* decWm = us;                       us += (size_t)H4 * Hdim;
    unsigned short* decWl = us;                       us += (size_t)H4 * Hdim;
    // projection weight planes (512x512 each)
    unsigned short* prWh = us;                        us += (size_t)Hdim * Hdim;
    unsigned short* prWm = us;                        us += (size_t)Hdim * Hdim;
    unsigned short* prWl = us;                        us += (size_t)Hdim * Hdim;
    unsigned short* pqWh = us;                        us += (size_t)Hdim * Hdim;
    unsigned short* pqWm = us;                        us += (size_t)Hdim * Hdim;
    unsigned short* pqWl = us;                        us += (size_t)Hdim * Hdim;

    float* out_map = (float*)d_out;                        // B*P floats
    float* out_ll  = out_map + (size_t)Bsz * Psteps;       // B floats

    static const int nodes[Psteps] = {0,0,0,0, 1,1,1,1, 2,2,2,2, 3,3,3,3};

    fold_kernel<<<H4, Gdim, 0, stream>>>(enc_Wih, enc_Whh, enc_b,
                                         dec_Wih, dec_Whh, dec_b,
                                         emb_W, dec0,
                                         encEh, encEm, encEl, encWh, encWm, encWl,
                                         decEh, decEm, decEl, decWh, decWm, decWl,
                                         encBI, decBI, v0bI);
    fold_proj<<<dim3(Hdim, 2), 256, 0, stream>>>(Wref2, Wq2,
                                                 prWh, prWm, prWl,
                                                 pqWh, pqWm, pqWl);

    const dim3 gBig(64, 16);    // gates grid: 1024 blocks (~3/CU by LDS)
    const dim3 gPr(64, 8);      // proj grid:  512 blocks = 2/CU

    // ---- encoder: 16 fused LSTM steps + u2[t] projection of h(t) ----
    for (int t = 0; t < Sseq; ++t) {
        float* ho = (t & 1) ? h0 : h1;
        float* co = (t & 1) ? c0 : c1;
        const float* hi = (t & 1) ? h1 : h0;
        const float* ci = (t & 1) ? c1 : c0;
        if (t == 0) {
            gates_mfma<<<gBig, 256, 0, stream>>>(
                encEh, encEm, encEl, Gdim,
                x, Sseq * Gdim, nullptr, 0,
                nullptr, nullptr, nullptr, 0, nullptr,
                encBI, ci, ho, co, 1);
        } else {
            gates_mfma<<<gBig, 256, 0, stream>>>(
                encEh, encEm, encEl, Gdim,
                x + t * Gdim, Sseq * Gdim, nullptr, 0,
                encWh, encWm, encWl, Hdim, hi,
                encBI, ci, ho, co, 0);
        }
        proj_mfma<<<gPr, 256, 0, stream>>>(prWh, prWm, prWl, ho, bref2,
                                           u2 + (size_t)t * Hdim, Sseq * Hdim);
    }

    // ---- decoder: 16 autoregressive steps ----
    for (int p = 0; p < Psteps; ++p) {
        const int u = Sseq + p;
        float* ho = (u & 1) ? h0 : h1;
        float* co = (u & 1) ? c0 : c1;
        const float* hi = (u & 1) ? h1 : h0;
        const float* ci = (u & 1) ? c1 : c0;
        if (p == 0) {
            gates_mfma<<<gBig, 256, 0, stream>>>(
                nullptr, nullptr, nullptr, 0,
                nullptr, 0, nullptr, 0,
                decWh, decWm, decWl, Hdim, hi,
                v0bI, ci, ho, co, 0);
        } else {
            gates_mfma<<<gBig, 256, 0, stream>>>(
                decEh, decEm, decEl, Gdim,
                x, Sseq * Gdim, nxt, Gdim,
                decWh, decWm, decWl, Hdim, hi,
                decBI, ci, ho, co, 0);
        }
        proj_mfma<<<gPr, 256, 0, stream>>>(pqWh, pqWm, pqWl, ho, bq2,
                                           qp, Hdim);
        attn_step<<<Bsz, 256, 0, stream>>>(qp, u2, Vec2, mask, ll, nxt,
                                           out_map, out_ll, p, nodes[p]);
    }
}

// Round 13
// 3280.159 us; speedup vs baseline: 1.1695x; 1.1695x over previous
//
#include <hip/hip_runtime.h>
#include <cstddef>

// Problem constants
#define Bsz  4096
#define Sseq 16
#define Gdim 128
#define Edim 256
#define Hdim 512
#define H4   2048
#define Psteps 16
#define BK   16

typedef short bfrag8 __attribute__((ext_vector_type(8)));   // 8 bf16 (4 VGPR)
typedef float f32x4  __attribute__((ext_vector_type(4)));   // MFMA acc

// Exact 3-way bf16 split of fp32 (truncation; residuals exactly representable:
// 24 mantissa bits = 8+8+8). a == hi+mid+lo exactly (normal range).
__device__ __forceinline__ void split3(float f, unsigned short& h,
                                       unsigned short& m, unsigned short& l) {
    unsigned u = __float_as_uint(f);
    h = (unsigned short)(u >> 16);
    float r1 = f - __uint_as_float(u & 0xffff0000u);
    unsigned u1 = __float_as_uint(r1);
    m = (unsigned short)(u1 >> 16);
    float r2 = r1 - __uint_as_float(u1 & 0xffff0000u);
    l = (unsigned short)(__float_as_uint(r2) >> 16);
}

// ---------------------------------------------------------------------------
// Fold kernel: gate-interleaved (row c = j*4+gate) weight prep, emitting
// bf16 hi/mid/lo planes for the MFMA path. Wih rows staged in LDS first
// (coalesced), e-loop reads LDS broadcasts -- same sequential FMA order.
// ---------------------------------------------------------------------------
__global__ void fold_kernel(const float* __restrict__ encWih,
                            const float* __restrict__ encWhh,
                            const float* __restrict__ enc_b,
                            const float* __restrict__ decWih,
                            const float* __restrict__ decWhh,
                            const float* __restrict__ dec_b,
                            const float* __restrict__ embW,
                            const float* __restrict__ dec0,
                            unsigned short* __restrict__ encEh,
                            unsigned short* __restrict__ encEm,
                            unsigned short* __restrict__ encEl,
                            unsigned short* __restrict__ encWh,
                            unsigned short* __restrict__ encWm,
                            unsigned short* __restrict__ encWl,
                            unsigned short* __restrict__ decEh,
                            unsigned short* __restrict__ decEm,
                            unsigned short* __restrict__ decEl,
                            unsigned short* __restrict__ decWh,
                            unsigned short* __restrict__ decWm,
                            unsigned short* __restrict__ decWl,
                            float* __restrict__ encBI, float* __restrict__ decBI,
                            float* __restrict__ v0bI) {
    __shared__ float rE[Edim], rD[Edim];
    const int o = blockIdx.x;            // original row 0..2047 (gate*512 + j)
    const int gate = o >> 9, j = o & 511;
    const int c = j * 4 + gate;          // interleaved row
    const int g = threadIdx.x;           // 0..127
    rE[g]        = encWih[(size_t)o * Edim + g];
    rE[g + Gdim] = encWih[(size_t)o * Edim + g + Gdim];
    rD[g]        = decWih[(size_t)o * Edim + g];
    rD[g + Gdim] = decWih[(size_t)o * Edim + g + Gdim];
    __syncthreads();

    float se = 0.f, sd = 0.f;
#pragma unroll 8
    for (int e = 0; e < Edim; ++e) {
        float w = embW[e * Gdim + g];
        se += rE[e] * w;                 // same sequential order as before
        sd += rD[e] * w;
    }
    unsigned short h, m, l;
    split3(se, h, m, l);
    encEh[(size_t)c * Gdim + g] = h; encEm[(size_t)c * Gdim + g] = m;
    encEl[(size_t)c * Gdim + g] = l;
    split3(sd, h, m, l);
    decEh[(size_t)c * Gdim + g] = h; decEm[(size_t)c * Gdim + g] = m;
    decEl[(size_t)c * Gdim + g] = l;
    for (int k = g; k < Hdim; k += Gdim) {
        split3(encWhh[(size_t)o * Hdim + k], h, m, l);
        encWh[(size_t)c * Hdim + k] = h; encWm[(size_t)c * Hdim + k] = m;
        encWl[(size_t)c * Hdim + k] = l;
        split3(decWhh[(size_t)o * Hdim + k], h, m, l);
        decWh[(size_t)c * Hdim + k] = h; decWm[(size_t)c * Hdim + k] = m;
        decWl[(size_t)c * Hdim + k] = l;
    }
    if (g == 0) {
        encBI[c] = enc_b[o];
        decBI[c] = dec_b[o];
        float s = dec_b[o];
        for (int e = 0; e < Edim; ++e) s += rD[e] * dec0[e];  // same order
        v0bI[c] = s;
    }
}

// ---------------------------------------------------------------------------
// Plane prep for the projection weights (Wref2, Wq2): row-major hi/mid/lo
// bf16 planes, 512x512 each. grid (512, 2).
// ---------------------------------------------------------------------------
__global__ __launch_bounds__(256) void fold_proj(
    const float* __restrict__ Wr, const float* __restrict__ Wq,
    unsigned short* __restrict__ rWh, unsigned short* __restrict__ rWm,
    unsigned short* __restrict__ rWl,
    unsigned short* __restrict__ qWh, unsigned short* __restrict__ qWm,
    unsigned short* __restrict__ qWl) {
    const int o = blockIdx.x;
    const float* src = blockIdx.y ? Wq : Wr;
    unsigned short* ph = blockIdx.y ? qWh : rWh;
    unsigned short* pm = blockIdx.y ? qWm : rWm;
    unsigned short* pl = blockIdx.y ? qWl : rWl;
    for (int k = threadIdx.x; k < Hdim; k += 256) {
        unsigned short h, m, l;
        split3(src[(size_t)o * Hdim + k], h, m, l);
        ph[(size_t)o * Hdim + k] = h;
        pm[(size_t)o * Hdim + k] = m;
        pl[(size_t)o * Hdim + k] = l;
    }
}

// ---------------------------------------------------------------------------
// MFMA gates GEMM + fused LSTM epilogue, fp32-exact via bf16x6 emulation.
// Round-13: round-11 block structure (128m x 128n, grid (32,16)=512=2/CU,
// dual LDS staging 80 KB, both-sides swizzles) but EIGHT waves per block
// (512 threads), each owning a 16m x 128n slice (acc 8x1). This doubles
// residency to 16 waves/CU = 4 waves/SIMD (was 2) with zero change to grid,
// per-block staging volume, chip-wide split3 totals, chunk order, or the
// 6-MFMA order -> bit-identical output. Round-12's mistake (shrinking
// blocks: staging overhead per MFMA doubled) is avoided: same blocks, just
// more waves sharing the same staging.
// ---------------------------------------------------------------------------
__global__ __launch_bounds__(512) void gates_mfma(
    const unsigned short* __restrict__ Wh1, const unsigned short* __restrict__ Wm1,
    const unsigned short* __restrict__ Wl1, int K1,
    const float* __restrict__ X, int ldx,
    const int* __restrict__ gather, int gmul,
    const unsigned short* __restrict__ Wh2, const unsigned short* __restrict__ Wm2,
    const unsigned short* __restrict__ Wl2, int K2,
    const float* __restrict__ Hin,
    const float* __restrict__ biasI,
    const float* __restrict__ c_in, float* __restrict__ h_out,
    float* __restrict__ c_out, int czero)
{
    __shared__ __align__(16) unsigned short wlds[2][3 * 4096]; // 48 KB
    __shared__ __align__(16) float alds[2][128 * 32];          // 32 KB

    const int tid = threadIdx.x;                 // 0..511
    const int wv = tid >> 6, lane = tid & 63;    // 8 waves
    const int lm = lane & 15, quad = lane >> 4;
    const int c0 = blockIdx.y * 128;             // block n-panel base row
    const int mB0 = blockIdx.x * 128;            // block batch base (128 rows)

    const int mrow = mB0 + wv * 16 + lm;         // this lane's act/output row

    // ---- weight staging: 128 rows x 4 units x 3 planes; 512 thr, 1 unit
    //      per thread per plane. Wave wv stages rows wv*16..wv*16+15.
    const int srow = wv * 16 + (lane >> 2);
    const int sqs = (lane & 3) ^ ((srow >> 1) & 3);   // pre-swizzled src unit
    const size_t roff1 = (size_t)(c0 + srow) * K1 + (size_t)(sqs * 8);
    const size_t roff2 = (size_t)(c0 + srow) * K2 + (size_t)(sqs * 8);

    // ---- act staging: 128 rows x 8 units; 2 issues x (8 waves x 8 rows) ----
    const int asw = ((lane & 7) ^ (lane >> 3)) * 4;   // swizzled src floats
    const float* asrcX[2];
    const float* asrcH[2];
#pragma unroll
    for (int i = 0; i < 2; ++i) {
        const int r = i * 64 + wv * 8 + (lane >> 3);
        const int m = mB0 + r;
        if (X) {
            size_t off = (size_t)m * ldx;
            if (gather) off += (size_t)gather[m] * gmul;
            asrcX[i] = X + off + asw;
        }
        if (Hin) asrcH[i] = Hin + (size_t)m * K2 + asw;
    }

    // ---- weight ds_read fragment offsets (ushort units), 8 n-tiles ----
    int boffW[8];
#pragma unroll
    for (int tn = 0; tn < 8; ++tn) {
        const int r = tn * 16 + lm;
        boffW[tn] = r * 32 + ((quad ^ ((r >> 1) & 3)) * 8);
    }
    // act ds_read offsets (float units): row ra, logical units 2q, 2q+1
    const int ra = wv * 16 + lm;
    const int boffA1 = ra * 32 + (((2 * quad)     ^ (lm & 7)) << 2);
    const int boffA2 = ra * 32 + (((2 * quad + 1) ^ (lm & 7)) << 2);

    auto stage = [&](int kcN, int buf) {
        const bool nX = kcN < K1;
        const int kb = nX ? kcN : kcN - K1;
        // weights: wave-uniform LDS base wv*512 ush, per-lane src
        unsigned short* lb = &wlds[buf][wv * 512];
        const unsigned short* gh = (nX ? Wh1 + roff1 : Wh2 + roff2) + kb;
        const unsigned short* gm = (nX ? Wm1 + roff1 : Wm2 + roff2) + kb;
        const unsigned short* gl = (nX ? Wl1 + roff1 : Wl2 + roff2) + kb;
        __builtin_amdgcn_global_load_lds(
            (const __attribute__((address_space(1))) void*)gh,
            (__attribute__((address_space(3))) void*)(lb), 16, 0, 0);
        __builtin_amdgcn_global_load_lds(
            (const __attribute__((address_space(1))) void*)gm,
            (__attribute__((address_space(3))) void*)(lb + 4096), 16, 0, 0);
        __builtin_amdgcn_global_load_lds(
            (const __attribute__((address_space(1))) void*)gl,
            (__attribute__((address_space(3))) void*)(lb + 8192), 16, 0, 0);
        // acts: 2 issues, wave covers 8 rows each
#pragma unroll
        for (int i = 0; i < 2; ++i) {
            float* ab = &alds[buf][(i * 64 + wv * 8) * 32];
            const float* src = (nX ? asrcX[i] : asrcH[i]) + kb;
            __builtin_amdgcn_global_load_lds(
                (const __attribute__((address_space(1))) void*)src,
                (__attribute__((address_space(3))) void*)ab, 16, 0, 0);
        }
    };

    f32x4 acc[8];
#pragma unroll
    for (int i = 0; i < 8; ++i) acc[i] = (f32x4){0.f, 0.f, 0.f, 0.f};

    const int KT = K1 + K2;
    stage(0, 0);
    int cur = 0;

    for (int kc = 0; kc < KT; kc += 32) {
        __syncthreads();                       // drains staged loads for buf[cur]
        if (kc + 32 < KT) stage(kc + 32, cur ^ 1);

        // this wave's single act fragment from LDS, split3 in VALU
        const float* abuf = alds[cur];
        float a8[8];
        *(float4*)&a8[0] = *(const float4*)(abuf + boffA1);
        *(float4*)&a8[4] = *(const float4*)(abuf + boffA2);
        bfrag8 bh, bm, bl;
#pragma unroll
        for (int j = 0; j < 8; ++j) {
            unsigned short h, m, l;
            split3(a8[j], h, m, l);
            bh[j] = (short)h; bm[j] = (short)m; bl[j] = (short)l;
        }

        const unsigned short* bufp = wlds[cur];
#pragma unroll
        for (int hh = 0; hh < 2; ++hh) {
            bfrag8 ah[4], am4[4], al[4];
#pragma unroll
            for (int t = 0; t < 4; ++t) {
                const int tn = hh * 4 + t;
                ah[t]  = *(const bfrag8*)(bufp + boffW[tn]);
                am4[t] = *(const bfrag8*)(bufp + 4096 + boffW[tn]);
                al[t]  = *(const bfrag8*)(bufp + 8192 + boffW[tn]);
            }
#pragma unroll
            for (int t = 0; t < 4; ++t) {
                const int tn = hh * 4 + t;
                f32x4 c = acc[tn];
                c = __builtin_amdgcn_mfma_f32_16x16x32_bf16(ah[t], bl, c, 0, 0, 0);
                c = __builtin_amdgcn_mfma_f32_16x16x32_bf16(al[t], bh, c, 0, 0, 0);
                c = __builtin_amdgcn_mfma_f32_16x16x32_bf16(am4[t], bm, c, 0, 0, 0);
                c = __builtin_amdgcn_mfma_f32_16x16x32_bf16(ah[t], bm, c, 0, 0, 0);
                c = __builtin_amdgcn_mfma_f32_16x16x32_bf16(am4[t], bh, c, 0, 0, 0);
                c = __builtin_amdgcn_mfma_f32_16x16x32_bf16(ah[t], bh, c, 0, 0, 0);
                acc[tn] = c;
            }
        }
        cur ^= 1;
    }

    // fused LSTM epilogue: lane's 4 acc regs = gates i,f,g,o of unit j
#pragma unroll
    for (int tn = 0; tn < 8; ++tn) {
        const int nb = c0 + tn * 16 + quad * 4;
        float4 bb = *(const float4*)(biasI + nb);
        const int j = nb >> 2;
        const size_t idx = (size_t)mrow * Hdim + j;
        float gi = acc[tn][0] + bb.x;
        float gf = acc[tn][1] + bb.y;
        float gg = acc[tn][2] + bb.z;
        float go = acc[tn][3] + bb.w;
        float si = 1.f / (1.f + expf(-gi));
        float sf = 1.f / (1.f + expf(-gf));
        float so = 1.f / (1.f + expf(-go));
        float co = czero ? 0.f : c_in[idx];
        float cn = si * tanhf(gg) + sf * co;
        c_out[idx] = cn;
        h_out[idx] = so * tanhf(cn);
    }
}

// ---------------------------------------------------------------------------
// MFMA projection GEMM: C = A @ W^T + bias (A 4096x512 fp32, W via bf16x6
// planes, K=512). Same bf16x6 scheme as gates (identical 6-term order).
// 64m x 64n block, 4 waves (wave = 16m x 64n, acc 4x1), grid (64,8)=512,
// dual LDS double-buffer staging with the proven both-sides swizzles.
// (round-11 version, verbatim — measured as part of the 3252us total)
// ---------------------------------------------------------------------------
__global__ __launch_bounds__(256) void proj_mfma(
    const unsigned short* __restrict__ Wh, const unsigned short* __restrict__ Wm,
    const unsigned short* __restrict__ Wl,
    const float* __restrict__ A,
    const float* __restrict__ bias,
    float* __restrict__ C, int ldc)
{
    __shared__ __align__(16) unsigned short wlds[2][3 * 2048]; // 24 KB
    __shared__ __align__(16) float alds[2][64 * 32];           // 16 KB

    const int tid = threadIdx.x;
    const int wv = tid >> 6, lane = tid & 63;
    const int lm = lane & 15, quad = lane >> 4;
    const int nB0 = blockIdx.y * 64;             // output-channel panel base
    const int mB0 = blockIdx.x * 64;             // batch tile base

    // ---- weight staging: 64 rows x 4 x 16B units, 256 threads, 1 issue ----
    const int rw = tid >> 2;                               // row 0..63
    const int sqw = (tid & 3) ^ ((rw >> 1) & 3);           // swizzled src unit
    const size_t wroff = (size_t)(nB0 + rw) * Hdim + (size_t)(sqw * 8);

    // ---- act staging: 2 issues x 32 rows x 8 x 16B units ----
    const int asw = ((lane & 7) ^ (lane >> 3)) * 4;        // swizzled src floats
    const float* asrc[2];
#pragma unroll
    for (int i = 0; i < 2; ++i) {
        const int r = i * 32 + wv * 8 + (lane >> 3);
        asrc[i] = A + (size_t)(mB0 + r) * Hdim + asw;
    }

    // ---- ds_read offsets ----
    int boffW[4];
#pragma unroll
    for (int tn = 0; tn < 4; ++tn) {
        const int r = tn * 16 + lm;
        boffW[tn] = r * 32 + ((quad ^ ((r >> 1) & 3)) * 8);
    }
    const int ra = wv * 16 + lm;                           // wave's act row
    const int boffA1 = ra * 32 + (((2 * quad)     ^ (lm & 7)) << 2);
    const int boffA2 = ra * 32 + (((2 * quad + 1) ^ (lm & 7)) << 2);

    auto stage = [&](int kb, int buf) {
        unsigned short* lb0 = &wlds[buf][wv * 512];
        __builtin_amdgcn_global_load_lds(
            (const __attribute__((address_space(1))) void*)(Wh + wroff + kb),
            (__attribute__((address_space(3))) void*)(lb0), 16, 0, 0);
        __builtin_amdgcn_global_load_lds(
            (const __attribute__((address_space(1))) void*)(Wm + wroff + kb),
            (__attribute__((address_space(3))) void*)(lb0 + 2048), 16, 0, 0);
        __builtin_amdgcn_global_load_lds(
            (const __attribute__((address_space(1))) void*)(Wl + wroff + kb),
            (__attribute__((address_space(3))) void*)(lb0 + 4096), 16, 0, 0);
#pragma unroll
        for (int i = 0; i < 2; ++i) {
            float* lb = &alds[buf][(i * 32 + wv * 8) * 32];
            __builtin_amdgcn_global_load_lds(
                (const __attribute__((address_space(1))) void*)(asrc[i] + kb),
                (__attribute__((address_space(3))) void*)lb, 16, 0, 0);
        }
    };

    f32x4 acc[4];
#pragma unroll
    for (int i = 0; i < 4; ++i) acc[i] = (f32x4){0.f, 0.f, 0.f, 0.f};

    stage(0, 0);
    int cur = 0;

    for (int kc = 0; kc < Hdim; kc += 32) {
        __syncthreads();
        if (kc + 32 < Hdim) stage(kc + 32, cur ^ 1);

        const float* abuf = alds[cur];
        float a8[8];
        *(float4*)&a8[0] = *(const float4*)(abuf + boffA1);
        *(float4*)&a8[4] = *(const float4*)(abuf + boffA2);
        bfrag8 bh, bm, bl;
#pragma unroll
        for (int j = 0; j < 8; ++j) {
            unsigned short h, m, l;
            split3(a8[j], h, m, l);
            bh[j] = (short)h; bm[j] = (short)m; bl[j] = (short)l;
        }

        const unsigned short* bufp = wlds[cur];
#pragma unroll
        for (int tn = 0; tn < 4; ++tn) {
            bfrag8 ah  = *(const bfrag8*)(bufp + boffW[tn]);
            bfrag8 am4 = *(const bfrag8*)(bufp + 2048 + boffW[tn]);
            bfrag8 al  = *(const bfrag8*)(bufp + 4096 + boffW[tn]);
            f32x4 c = acc[tn];
            c = __builtin_amdgcn_mfma_f32_16x16x32_bf16(ah,  bl, c, 0, 0, 0);
            c = __builtin_amdgcn_mfma_f32_16x16x32_bf16(al,  bh, c, 0, 0, 0);
            c = __builtin_amdgcn_mfma_f32_16x16x32_bf16(am4, bm, c, 0, 0, 0);
            c = __builtin_amdgcn_mfma_f32_16x16x32_bf16(ah,  bm, c, 0, 0, 0);
            c = __builtin_amdgcn_mfma_f32_16x16x32_bf16(am4, bh, c, 0, 0, 0);
            c = __builtin_amdgcn_mfma_f32_16x16x32_bf16(ah,  bh, c, 0, 0, 0);
            acc[tn] = c;
        }
        cur ^= 1;
    }

    // epilogue: lane reg r of acc[tn] = channel nB0+tn*16+quad*4+r, batch
    // row mB0+wv*16+lm (planes NOT gate-interleaved).
    const int m = mB0 + wv * 16 + lm;
#pragma unroll
    for (int tn = 0; tn < 4; ++tn) {
        const int n = nB0 + tn * 16 + quad * 4;
        float4 bb = *(const float4*)(bias + n);
        float4 o;
        o.x = acc[tn][0] + bb.x;
        o.y = acc[tn][1] + bb.y;
        o.z = acc[tn][2] + bb.z;
        o.w = acc[tn][3] + bb.w;
        *(float4*)(C + (size_t)m * ldc + n) = o;
    }
}

// ---------------------------------------------------------------------------
// Attention + log-softmax + argmax + state update.
// ---------------------------------------------------------------------------
__global__ __launch_bounds__(256) void attn_step(const float* __restrict__ qp,
                                                 const float* __restrict__ u2,
                                                 const float* __restrict__ Vec2,
                                                 float* __restrict__ mask,
                                                 float* __restrict__ ll_ws,
                                                 int* __restrict__ nxt,
                                                 float* __restrict__ out_map,
                                                 float* __restrict__ out_ll,
                                                 int step, int node) {
    const int b = blockIdx.x;
    __shared__ float qpS[Hdim];
    __shared__ float vS[Hdim];
    __shared__ float logitS[Sseq];
    const int tid = threadIdx.x;
    qpS[tid]       = qp[(size_t)b * Hdim + tid];
    qpS[tid + 256] = qp[(size_t)b * Hdim + 256 + tid];
    vS[tid]        = Vec2[tid];
    vS[tid + 256]  = Vec2[256 + tid];
    __syncthreads();

    const int wave = tid >> 6, lane = tid & 63;
    for (int si = 0; si < 4; ++si) {
        int s = wave * 4 + si;
        const float* u2p = u2 + ((size_t)b * Sseq + s) * Hdim;
        float sum = 0.f;
#pragma unroll
        for (int i = 0; i < 8; ++i) {
            int hh = lane + i * 64;
            sum += vS[hh] * tanhf(qpS[hh] + u2p[hh]);
        }
        for (int off = 32; off > 0; off >>= 1) sum += __shfl_down(sum, off);
        if (lane == 0) {
            float pen = step ? mask[b * Sseq + s] * 1e8f : 0.f;
            logitS[s] = 10.f * sum - pen;
        }
    }
    __syncthreads();

    if (tid == 0) {
        float mx = logitS[0];
        int am = 0;
        for (int s = 1; s < Sseq; ++s)
            if (logitS[s] > mx) { mx = logitS[s]; am = s; }
        float se = 0.f;
        for (int s = 0; s < Sseq; ++s) se += expf(logitS[s] - mx);
        float lp = -logf(se);
        float llv = (step ? ll_ws[b] : 0.f) + lp;
        ll_ws[b] = llv;
        out_ll[b] = llv;
        nxt[b] = am;
        if (step == 0) {
            for (int s = 0; s < Sseq; ++s) mask[b * Sseq + s] = (s == am) ? 1.f : 0.f;
        } else {
            mask[b * Sseq + am] += 1.f;
        }
        out_map[b * Sseq + am] = (float)node;
    }
}

// ---------------------------------------------------------------------------
extern "C" void kernel_launch(void* const* d_in, const int* in_sizes, int n_in,
                              void* d_out, int out_size, void* d_ws, size_t ws_size,
                              hipStream_t stream) {
    const float* x       = (const float*)d_in[0];
    const float* emb_W   = (const float*)d_in[1];
    const float* enc_Wih = (const float*)d_in[2];
    const float* enc_Whh = (const float*)d_in[3];
    const float* enc_b   = (const float*)d_in[4];
    const float* dec_Wih = (const float*)d_in[5];
    const float* dec_Whh = (const float*)d_in[6];
    const float* dec_b   = (const float*)d_in[7];
    const float* Wq2     = (const float*)d_in[8];
    const float* bq2     = (const float*)d_in[9];
    const float* Wref2   = (const float*)d_in[10];
    const float* bref2   = (const float*)d_in[11];
    const float* Vec2    = (const float*)d_in[12];
    const float* dec0    = (const float*)d_in[13];

    // workspace layout — ~195 MB
    float* ws      = (float*)d_ws;
    float* u2      = ws;                                   // B*S*H fp32
    float* h0      = u2 + (size_t)Bsz * Sseq * Hdim;       // B*H each
    float* c0      = h0 + (size_t)Bsz * Hdim;
    float* h1      = c0 + (size_t)Bsz * Hdim;
    float* c1      = h1 + (size_t)Bsz * Hdim;
    float* qp      = c1 + (size_t)Bsz * Hdim;
    float* mask    = qp + (size_t)Bsz * Hdim;              // B*S
    float* ll      = mask + (size_t)Bsz * Sseq;            // B
    int*   nxt     = (int*)(ll + Bsz);                     // B
    float* encBI   = (float*)(nxt + Bsz);                  // 2048 each
    float* decBI   = encBI + H4;
    float* v0bI    = decBI + H4;
    // bf16 weight planes (ushort)
    unsigned short* us = (unsigned short*)(v0bI + H4);
    unsigned short* encEh = us;                       us += (size_t)H4 * Gdim;
    unsigned short* encEm = us;                       us += (size_t)H4 * Gdim;
    unsigned short* encEl = us;                       us += (size_t)H4 * Gdim;
    unsigned short* encWh = us;                       us += (size_t)H4 * Hdim;
    unsigned short* encWm = us;                       us += (size_t)H4 * Hdim;
    unsigned short* encWl = us;                       us += (size_t)H4 * Hdim;
    unsigned short* decEh = us;                       us += (size_t)H4 * Gdim;
    unsigned short* decEm = us;                       us += (size_t)H4 * Gdim;
    unsigned short* decEl = us;                       us += (size_t)H4 * Gdim;
    unsigned short* decWh = us;                       us += (size_t)H4 * Hdim;
    unsigned short* decWm = us;                       us += (size_t)H4 * Hdim;
    unsigned short* decWl = us;                       us += (size_t)H4 * Hdim;
    // projection weight planes (512x512 each)
    unsigned short* prWh = us;                        us += (size_t)Hdim * Hdim;
    unsigned short* prWm = us;                        us += (size_t)Hdim * Hdim;
    unsigned short* prWl = us;                        us += (size_t)Hdim * Hdim;
    unsigned short* pqWh = us;                        us += (size_t)Hdim * Hdim;
    unsigned short* pqWm = us;                        us += (size_t)Hdim * Hdim;
    unsigned short* pqWl = us;                        us += (size_t)Hdim * Hdim;

    float* out_map = (float*)d_out;                        // B*P floats
    float* out_ll  = out_map + (size_t)Bsz * Psteps;       // B floats

    static const int nodes[Psteps] = {0,0,0,0, 1,1,1,1, 2,2,2,2, 3,3,3,3};

    fold_kernel<<<H4, Gdim, 0, stream>>>(enc_Wih, enc_Whh, enc_b,
                                         dec_Wih, dec_Whh, dec_b,
                                         emb_W, dec0,
                                         encEh, encEm, encEl, encWh, encWm, encWl,
                                         decEh, decEm, decEl, decWh, decWm, decWl,
                                         encBI, decBI, v0bI);
    fold_proj<<<dim3(Hdim, 2), 256, 0, stream>>>(Wref2, Wq2,
                                                 prWh, prWm, prWl,
                                                 pqWh, pqWm, pqWl);

    const dim3 gBig(32, 16);    // gates grid: 512 blocks (512 thr) = 2/CU
    const dim3 gPr(64, 8);      // proj grid:  512 blocks = 2/CU

    // ---- encoder: 16 fused LSTM steps + u2[t] projection of h(t) ----
    for (int t = 0; t < Sseq; ++t) {
        float* ho = (t & 1) ? h0 : h1;
        float* co = (t & 1) ? c0 : c1;
        const float* hi = (t & 1) ? h1 : h0;
        const float* ci = (t & 1) ? c1 : c0;
        if (t == 0) {
            gates_mfma<<<gBig, 512, 0, stream>>>(
                encEh, encEm, encEl, Gdim,
                x, Sseq * Gdim, nullptr, 0,
                nullptr, nullptr, nullptr, 0, nullptr,
                encBI, ci, ho, co, 1);
        } else {
            gates_mfma<<<gBig, 512, 0, stream>>>(
                encEh, encEm, encEl, Gdim,
                x + t * Gdim, Sseq * Gdim, nullptr, 0,
                encWh, encWm, encWl, Hdim, hi,
                encBI, ci, ho, co, 0);
        }
        proj_mfma<<<gPr, 256, 0, stream>>>(prWh, prWm, prWl, ho, bref2,
                                           u2 + (size_t)t * Hdim, Sseq * Hdim);
    }

    // ---- decoder: 16 autoregressive steps ----
    for (int p = 0; p < Psteps; ++p) {
        const int u = Sseq + p;
        float* ho = (u & 1) ? h0 : h1;
        float* co = (u & 1) ? c0 : c1;
        const float* hi = (u & 1) ? h1 : h0;
        const float* ci = (u & 1) ? c1 : c0;
        if (p == 0) {
            gates_mfma<<<gBig, 512, 0, stream>>>(
                nullptr, nullptr, nullptr, 0,
                nullptr, 0, nullptr, 0,
                decWh, decWm, decWl, Hdim, hi,
                v0bI, ci, ho, co, 0);
        } else {
            gates_mfma<<<gBig, 512, 0, stream>>>(
                decEh, decEm, decEl, Gdim,
                x, Sseq * Gdim, nxt, Gdim,
                decWh, decWm, decWl, Hdim, hi,
                decBI, ci, ho, co, 0);
        }
        proj_mfma<<<gPr, 256, 0, stream>>>(pqWh, pqWm, pqWl, ho, bq2,
                                           qp, Hdim);
        attn_step<<<Bsz, 256, 0, stream>>>(qp, u2, Vec2, mask, ll, nxt,
                                           out_map, out_ll, p, nodes[p]);
    }
}

// Round 14
// 3262.597 us; speedup vs baseline: 1.1758x; 1.0054x over previous
//
#include <hip/hip_runtime.h>
#include <cstddef>

// Problem constants
#define Bsz  4096
#define Sseq 16
#define Gdim 128
#define Edim 256
#define Hdim 512
#define H4   2048
#define Psteps 16
#define BK   16

typedef short bfrag8 __attribute__((ext_vector_type(8)));   // 8 bf16 (4 VGPR)
typedef float f32x4  __attribute__((ext_vector_type(4)));   // MFMA acc

// Exact 3-way bf16 split of fp32 (truncation; residuals exactly representable:
// 24 mantissa bits = 8+8+8). a == hi+mid+lo exactly (normal range).
__device__ __forceinline__ void split3(float f, unsigned short& h,
                                       unsigned short& m, unsigned short& l) {
    unsigned u = __float_as_uint(f);
    h = (unsigned short)(u >> 16);
    float r1 = f - __uint_as_float(u & 0xffff0000u);
    unsigned u1 = __float_as_uint(r1);
    m = (unsigned short)(u1 >> 16);
    float r2 = r1 - __uint_as_float(u1 & 0xffff0000u);
    l = (unsigned short)(__float_as_uint(r2) >> 16);
}

// ---------------------------------------------------------------------------
// Fold kernel: gate-interleaved (row c = j*4+gate) weight prep, emitting
// bf16 hi/mid/lo planes for the MFMA path. Wih rows staged in LDS first
// (coalesced), e-loop reads LDS broadcasts -- same sequential FMA order.
// ---------------------------------------------------------------------------
__global__ void fold_kernel(const float* __restrict__ encWih,
                            const float* __restrict__ encWhh,
                            const float* __restrict__ enc_b,
                            const float* __restrict__ decWih,
                            const float* __restrict__ decWhh,
                            const float* __restrict__ dec_b,
                            const float* __restrict__ embW,
                            const float* __restrict__ dec0,
                            unsigned short* __restrict__ encEh,
                            unsigned short* __restrict__ encEm,
                            unsigned short* __restrict__ encEl,
                            unsigned short* __restrict__ encWh,
                            unsigned short* __restrict__ encWm,
                            unsigned short* __restrict__ encWl,
                            unsigned short* __restrict__ decEh,
                            unsigned short* __restrict__ decEm,
                            unsigned short* __restrict__ decEl,
                            unsigned short* __restrict__ decWh,
                            unsigned short* __restrict__ decWm,
                            unsigned short* __restrict__ decWl,
                            float* __restrict__ encBI, float* __restrict__ decBI,
                            float* __restrict__ v0bI) {
    __shared__ float rE[Edim], rD[Edim];
    const int o = blockIdx.x;            // original row 0..2047 (gate*512 + j)
    const int gate = o >> 9, j = o & 511;
    const int c = j * 4 + gate;          // interleaved row
    const int g = threadIdx.x;           // 0..127
    rE[g]        = encWih[(size_t)o * Edim + g];
    rE[g + Gdim] = encWih[(size_t)o * Edim + g + Gdim];
    rD[g]        = decWih[(size_t)o * Edim + g];
    rD[g + Gdim] = decWih[(size_t)o * Edim + g + Gdim];
    __syncthreads();

    float se = 0.f, sd = 0.f;
#pragma unroll 8
    for (int e = 0; e < Edim; ++e) {
        float w = embW[e * Gdim + g];
        se += rE[e] * w;                 // same sequential order as before
        sd += rD[e] * w;
    }
    unsigned short h, m, l;
    split3(se, h, m, l);
    encEh[(size_t)c * Gdim + g] = h; encEm[(size_t)c * Gdim + g] = m;
    encEl[(size_t)c * Gdim + g] = l;
    split3(sd, h, m, l);
    decEh[(size_t)c * Gdim + g] = h; decEm[(size_t)c * Gdim + g] = m;
    decEl[(size_t)c * Gdim + g] = l;
    for (int k = g; k < Hdim; k += Gdim) {
        split3(encWhh[(size_t)o * Hdim + k], h, m, l);
        encWh[(size_t)c * Hdim + k] = h; encWm[(size_t)c * Hdim + k] = m;
        encWl[(size_t)c * Hdim + k] = l;
        split3(decWhh[(size_t)o * Hdim + k], h, m, l);
        decWh[(size_t)c * Hdim + k] = h; decWm[(size_t)c * Hdim + k] = m;
        decWl[(size_t)c * Hdim + k] = l;
    }
    if (g == 0) {
        encBI[c] = enc_b[o];
        decBI[c] = dec_b[o];
        float s = dec_b[o];
        for (int e = 0; e < Edim; ++e) s += rD[e] * dec0[e];  // same order
        v0bI[c] = s;
    }
}

// ---------------------------------------------------------------------------
// Plane prep for the projection weights (Wref2, Wq2): row-major hi/mid/lo
// bf16 planes, 512x512 each. grid (512, 2).
// ---------------------------------------------------------------------------
__global__ __launch_bounds__(256) void fold_proj(
    const float* __restrict__ Wr, const float* __restrict__ Wq,
    unsigned short* __restrict__ rWh, unsigned short* __restrict__ rWm,
    unsigned short* __restrict__ rWl,
    unsigned short* __restrict__ qWh, unsigned short* __restrict__ qWm,
    unsigned short* __restrict__ qWl) {
    const int o = blockIdx.x;
    const float* src = blockIdx.y ? Wq : Wr;
    unsigned short* ph = blockIdx.y ? qWh : rWh;
    unsigned short* pm = blockIdx.y ? qWm : rWm;
    unsigned short* pl = blockIdx.y ? qWl : rWl;
    for (int k = threadIdx.x; k < Hdim; k += 256) {
        unsigned short h, m, l;
        split3(src[(size_t)o * Hdim + k], h, m, l);
        ph[(size_t)o * Hdim + k] = h;
        pm[(size_t)o * Hdim + k] = m;
        pl[(size_t)o * Hdim + k] = l;
    }
}

// ---------------------------------------------------------------------------
// MFMA gates GEMM + fused LSTM epilogue, fp32-exact via bf16x6 emulation.
// Round-14: round-13 shell (128m x 128n block, 8 waves / 512 thr, grid
// (32,16)=512=2/CU, dual LDS staging 80 KB) but the wave tile is rebalanced
// from 16m x 128n to 32m x 64n (4 wm x 2 wn). Round-13's m-slice waves each
// read ALL staged weights (8x duplication -> ~208 KB LDS reads per block per
// chunk); the LDS pipe, not MFMA, became the binder (MfmaUtil stuck at 41%).
// 32m x 64n minimizes per-wave traffic (weights 192B/n-col + acts 128B/m-row
// per chunk): 131 KB/block (-37%), act split3 duplicated only 2x. Per-(n,m)
// accumulation order, chunk order, 6-MFMA sequence unchanged -> bit-identical.
// ---------------------------------------------------------------------------
__global__ __launch_bounds__(512) void gates_mfma(
    const unsigned short* __restrict__ Wh1, const unsigned short* __restrict__ Wm1,
    const unsigned short* __restrict__ Wl1, int K1,
    const float* __restrict__ X, int ldx,
    const int* __restrict__ gather, int gmul,
    const unsigned short* __restrict__ Wh2, const unsigned short* __restrict__ Wm2,
    const unsigned short* __restrict__ Wl2, int K2,
    const float* __restrict__ Hin,
    const float* __restrict__ biasI,
    const float* __restrict__ c_in, float* __restrict__ h_out,
    float* __restrict__ c_out, int czero)
{
    __shared__ __align__(16) unsigned short wlds[2][3 * 4096]; // 48 KB
    __shared__ __align__(16) float alds[2][128 * 32];          // 32 KB

    const int tid = threadIdx.x;                 // 0..511
    const int wv = tid >> 6, lane = tid & 63;    // 8 waves
    const int wm4 = wv >> 1, wn2 = wv & 1;       // 4 m-groups x 2 n-groups
    const int lm = lane & 15, quad = lane >> 4;
    const int c0 = blockIdx.y * 128;             // block n-panel base row
    const int mB0 = blockIdx.x * 128;            // block batch base (128 rows)

    // this wave's output rows: wm4*32 + tm*16 + lm, tm in {0,1}
    int mrow[2];
#pragma unroll
    for (int tm = 0; tm < 2; ++tm) mrow[tm] = mB0 + wm4 * 32 + tm * 16 + lm;

    // ---- weight staging: 128 rows x 4 units x 3 planes; 512 thr, 1 unit
    //      per thread per plane. Wave wv stages rows wv*16..wv*16+15.
    const int srow = wv * 16 + (lane >> 2);
    const int sqs = (lane & 3) ^ ((srow >> 1) & 3);   // pre-swizzled src unit
    const size_t roff1 = (size_t)(c0 + srow) * K1 + (size_t)(sqs * 8);
    const size_t roff2 = (size_t)(c0 + srow) * K2 + (size_t)(sqs * 8);

    // ---- act staging: 128 rows x 8 units; 2 issues x (8 waves x 8 rows) ----
    const int asw = ((lane & 7) ^ (lane >> 3)) * 4;   // swizzled src floats
    const float* asrcX[2];
    const float* asrcH[2];
#pragma unroll
    for (int i = 0; i < 2; ++i) {
        const int r = i * 64 + wv * 8 + (lane >> 3);
        const int m = mB0 + r;
        if (X) {
            size_t off = (size_t)m * ldx;
            if (gather) off += (size_t)gather[m] * gmul;
            asrcX[i] = X + off + asw;
        }
        if (Hin) asrcH[i] = Hin + (size_t)m * K2 + asw;
    }

    // ---- weight ds_read fragment offsets (ushort units), 4 n-tiles ----
    int boffW[4];
#pragma unroll
    for (int tn = 0; tn < 4; ++tn) {
        const int r = wn2 * 64 + tn * 16 + lm;
        boffW[tn] = r * 32 + ((quad ^ ((r >> 1) & 3)) * 8);
    }
    // act ds_read offsets (float units): rows ra[tm], logical units 2q, 2q+1
    int boffA1[2], boffA2[2];
#pragma unroll
    for (int tm = 0; tm < 2; ++tm) {
        const int ra = wm4 * 32 + tm * 16 + lm;   // ra&7 == lm&7
        boffA1[tm] = ra * 32 + (((2 * quad)     ^ (lm & 7)) << 2);
        boffA2[tm] = ra * 32 + (((2 * quad + 1) ^ (lm & 7)) << 2);
    }

    auto stage = [&](int kcN, int buf) {
        const bool nX = kcN < K1;
        const int kb = nX ? kcN : kcN - K1;
        // weights: wave-uniform LDS base wv*512 ush, per-lane src
        unsigned short* lb = &wlds[buf][wv * 512];
        const unsigned short* gh = (nX ? Wh1 + roff1 : Wh2 + roff2) + kb;
        const unsigned short* gm = (nX ? Wm1 + roff1 : Wm2 + roff2) + kb;
        const unsigned short* gl = (nX ? Wl1 + roff1 : Wl2 + roff2) + kb;
        __builtin_amdgcn_global_load_lds(
            (const __attribute__((address_space(1))) void*)gh,
            (__attribute__((address_space(3))) void*)(lb), 16, 0, 0);
        __builtin_amdgcn_global_load_lds(
            (const __attribute__((address_space(1))) void*)gm,
            (__attribute__((address_space(3))) void*)(lb + 4096), 16, 0, 0);
        __builtin_amdgcn_global_load_lds(
            (const __attribute__((address_space(1))) void*)gl,
            (__attribute__((address_space(3))) void*)(lb + 8192), 16, 0, 0);
        // acts: 2 issues, wave covers 8 rows each
#pragma unroll
        for (int i = 0; i < 2; ++i) {
            float* ab = &alds[buf][(i * 64 + wv * 8) * 32];
            const float* src = (nX ? asrcX[i] : asrcH[i]) + kb;
            __builtin_amdgcn_global_load_lds(
                (const __attribute__((address_space(1))) void*)src,
                (__attribute__((address_space(3))) void*)ab, 16, 0, 0);
        }
    };

    f32x4 acc[4][2];
#pragma unroll
    for (int i = 0; i < 4; ++i)
#pragma unroll
        for (int j = 0; j < 2; ++j) acc[i][j] = (f32x4){0.f, 0.f, 0.f, 0.f};

    const int KT = K1 + K2;
    stage(0, 0);
    int cur = 0;

    for (int kc = 0; kc < KT; kc += 32) {
        __syncthreads();                       // drains staged loads for buf[cur]
        if (kc + 32 < KT) stage(kc + 32, cur ^ 1);

        // this wave's two act fragments from LDS, split3 in VALU
        const float* abuf = alds[cur];
        bfrag8 bh[2], bm[2], bl[2];
#pragma unroll
        for (int tm = 0; tm < 2; ++tm) {
            float a8[8];
            *(float4*)&a8[0] = *(const float4*)(abuf + boffA1[tm]);
            *(float4*)&a8[4] = *(const float4*)(abuf + boffA2[tm]);
#pragma unroll
            for (int j = 0; j < 8; ++j) {
                unsigned short h, m, l;
                split3(a8[j], h, m, l);
                bh[tm][j] = (short)h; bm[tm][j] = (short)m; bl[tm][j] = (short)l;
            }
        }

        const unsigned short* bufp = wlds[cur];
#pragma unroll
        for (int tn = 0; tn < 4; ++tn) {
            bfrag8 ah  = *(const bfrag8*)(bufp + boffW[tn]);
            bfrag8 am4 = *(const bfrag8*)(bufp + 4096 + boffW[tn]);
            bfrag8 al  = *(const bfrag8*)(bufp + 8192 + boffW[tn]);
#pragma unroll
            for (int tm = 0; tm < 2; ++tm) {
                f32x4 c = acc[tn][tm];
                c = __builtin_amdgcn_mfma_f32_16x16x32_bf16(ah,  bl[tm], c, 0, 0, 0);
                c = __builtin_amdgcn_mfma_f32_16x16x32_bf16(al,  bh[tm], c, 0, 0, 0);
                c = __builtin_amdgcn_mfma_f32_16x16x32_bf16(am4, bm[tm], c, 0, 0, 0);
                c = __builtin_amdgcn_mfma_f32_16x16x32_bf16(ah,  bm[tm], c, 0, 0, 0);
                c = __builtin_amdgcn_mfma_f32_16x16x32_bf16(am4, bh[tm], c, 0, 0, 0);
                c = __builtin_amdgcn_mfma_f32_16x16x32_bf16(ah,  bh[tm], c, 0, 0, 0);
                acc[tn][tm] = c;
            }
        }
        cur ^= 1;
    }

    // fused LSTM epilogue: lane's 4 acc regs = gates i,f,g,o of unit j
#pragma unroll
    for (int tn = 0; tn < 4; ++tn) {
        const int nb = c0 + wn2 * 64 + tn * 16 + quad * 4;
        float4 bb = *(const float4*)(biasI + nb);
        const int j = nb >> 2;
#pragma unroll
        for (int tm = 0; tm < 2; ++tm) {
            const size_t idx = (size_t)mrow[tm] * Hdim + j;
            float gi = acc[tn][tm][0] + bb.x;
            float gf = acc[tn][tm][1] + bb.y;
            float gg = acc[tn][tm][2] + bb.z;
            float go = acc[tn][tm][3] + bb.w;
            float si = 1.f / (1.f + expf(-gi));
            float sf = 1.f / (1.f + expf(-gf));
            float so = 1.f / (1.f + expf(-go));
            float co = czero ? 0.f : c_in[idx];
            float cn = si * tanhf(gg) + sf * co;
            c_out[idx] = cn;
            h_out[idx] = so * tanhf(cn);
        }
    }
}

// ---------------------------------------------------------------------------
// MFMA projection GEMM: C = A @ W^T + bias (A 4096x512 fp32, W via bf16x6
// planes, K=512). Same bf16x6 scheme as gates (identical 6-term order).
// 64m x 64n block, 4 waves (wave = 16m x 64n, acc 4x1), grid (64,8)=512,
// dual LDS double-buffer staging with the proven both-sides swizzles.
// (round-11 version, verbatim)
// ---------------------------------------------------------------------------
__global__ __launch_bounds__(256) void proj_mfma(
    const unsigned short* __restrict__ Wh, const unsigned short* __restrict__ Wm,
    const unsigned short* __restrict__ Wl,
    const float* __restrict__ A,
    const float* __restrict__ bias,
    float* __restrict__ C, int ldc)
{
    __shared__ __align__(16) unsigned short wlds[2][3 * 2048]; // 24 KB
    __shared__ __align__(16) float alds[2][64 * 32];           // 16 KB

    const int tid = threadIdx.x;
    const int wv = tid >> 6, lane = tid & 63;
    const int lm = lane & 15, quad = lane >> 4;
    const int nB0 = blockIdx.y * 64;             // output-channel panel base
    const int mB0 = blockIdx.x * 64;             // batch tile base

    // ---- weight staging: 64 rows x 4 x 16B units, 256 threads, 1 issue ----
    const int rw = tid >> 2;                               // row 0..63
    const int sqw = (tid & 3) ^ ((rw >> 1) & 3);           // swizzled src unit
    const size_t wroff = (size_t)(nB0 + rw) * Hdim + (size_t)(sqw * 8);

    // ---- act staging: 2 issues x 32 rows x 8 x 16B units ----
    const int asw = ((lane & 7) ^ (lane >> 3)) * 4;        // swizzled src floats
    const float* asrc[2];
#pragma unroll
    for (int i = 0; i < 2; ++i) {
        const int r = i * 32 + wv * 8 + (lane >> 3);
        asrc[i] = A + (size_t)(mB0 + r) * Hdim + asw;
    }

    // ---- ds_read offsets ----
    int boffW[4];
#pragma unroll
    for (int tn = 0; tn < 4; ++tn) {
        const int r = tn * 16 + lm;
        boffW[tn] = r * 32 + ((quad ^ ((r >> 1) & 3)) * 8);
    }
    const int ra = wv * 16 + lm;                           // wave's act row
    const int boffA1 = ra * 32 + (((2 * quad)     ^ (lm & 7)) << 2);
    const int boffA2 = ra * 32 + (((2 * quad + 1) ^ (lm & 7)) << 2);

    auto stage = [&](int kb, int buf) {
        unsigned short* lb0 = &wlds[buf][wv * 512];
        __builtin_amdgcn_global_load_lds(
            (const __attribute__((address_space(1))) void*)(Wh + wroff + kb),
            (__attribute__((address_space(3))) void*)(lb0), 16, 0, 0);
        __builtin_amdgcn_global_load_lds(
            (const __attribute__((address_space(1))) void*)(Wm + wroff + kb),
            (__attribute__((address_space(3))) void*)(lb0 + 2048), 16, 0, 0);
        __builtin_amdgcn_global_load_lds(
            (const __attribute__((address_space(1))) void*)(Wl + wroff + kb),
            (__attribute__((address_space(3))) void*)(lb0 + 4096), 16, 0, 0);
#pragma unroll
        for (int i = 0; i < 2; ++i) {
            float* lb = &alds[buf][(i * 32 + wv * 8) * 32];
            __builtin_amdgcn_global_load_lds(
                (const __attribute__((address_space(1))) void*)(asrc[i] + kb),
                (__attribute__((address_space(3))) void*)lb, 16, 0, 0);
        }
    };

    f32x4 acc[4];
#pragma unroll
    for (int i = 0; i < 4; ++i) acc[i] = (f32x4){0.f, 0.f, 0.f, 0.f};

    stage(0, 0);
    int cur = 0;

    for (int kc = 0; kc < Hdim; kc += 32) {
        __syncthreads();
        if (kc + 32 < Hdim) stage(kc + 32, cur ^ 1);

        const float* abuf = alds[cur];
        float a8[8];
        *(float4*)&a8[0] = *(const float4*)(abuf + boffA1);
        *(float4*)&a8[4] = *(const float4*)(abuf + boffA2);
        bfrag8 bh, bm, bl;
#pragma unroll
        for (int j = 0; j < 8; ++j) {
            unsigned short h, m, l;
            split3(a8[j], h, m, l);
            bh[j] = (short)h; bm[j] = (short)m; bl[j] = (short)l;
        }

        const unsigned short* bufp = wlds[cur];
#pragma unroll
        for (int tn = 0; tn < 4; ++tn) {
            bfrag8 ah  = *(const bfrag8*)(bufp + boffW[tn]);
            bfrag8 am4 = *(const bfrag8*)(bufp + 2048 + boffW[tn]);
            bfrag8 al  = *(const bfrag8*)(bufp + 4096 + boffW[tn]);
            f32x4 c = acc[tn];
            c = __builtin_amdgcn_mfma_f32_16x16x32_bf16(ah,  bl, c, 0, 0, 0);
            c = __builtin_amdgcn_mfma_f32_16x16x32_bf16(al,  bh, c, 0, 0, 0);
            c = __builtin_amdgcn_mfma_f32_16x16x32_bf16(am4, bm, c, 0, 0, 0);
            c = __builtin_amdgcn_mfma_f32_16x16x32_bf16(ah,  bm, c, 0, 0, 0);
            c = __builtin_amdgcn_mfma_f32_16x16x32_bf16(am4, bh, c, 0, 0, 0);
            c = __builtin_amdgcn_mfma_f32_16x16x32_bf16(ah,  bh, c, 0, 0, 0);
            acc[tn] = c;
        }
        cur ^= 1;
    }

    // epilogue: lane reg r of acc[tn] = channel nB0+tn*16+quad*4+r, batch
    // row mB0+wv*16+lm (planes NOT gate-interleaved).
    const int m = mB0 + wv * 16 + lm;
#pragma unroll
    for (int tn = 0; tn < 4; ++tn) {
        const int n = nB0 + tn * 16 + quad * 4;
        float4 bb = *(const float4*)(bias + n);
        float4 o;
        o.x = acc[tn][0] + bb.x;
        o.y = acc[tn][1] + bb.y;
        o.z = acc[tn][2] + bb.z;
        o.w = acc[tn][3] + bb.w;
        *(float4*)(C + (size_t)m * ldc + n) = o;
    }
}

// ---------------------------------------------------------------------------
// Attention + log-softmax + argmax + state update.
// ---------------------------------------------------------------------------
__global__ __launch_bounds__(256) void attn_step(const float* __restrict__ qp,
                                                 const float* __restrict__ u2,
                                                 const float* __restrict__ Vec2,
                                                 float* __restrict__ mask,
                                                 float* __restrict__ ll_ws,
                                                 int* __restrict__ nxt,
                                                 float* __restrict__ out_map,
                                                 float* __restrict__ out_ll,
                                                 int step, int node) {
    const int b = blockIdx.x;
    __shared__ float qpS[Hdim];
    __shared__ float vS[Hdim];
    __shared__ float logitS[Sseq];
    const int tid = threadIdx.x;
    qpS[tid]       = qp[(size_t)b * Hdim + tid];
    qpS[tid + 256] = qp[(size_t)b * Hdim + 256 + tid];
    vS[tid]        = Vec2[tid];
    vS[tid + 256]  = Vec2[256 + tid];
    __syncthreads();

    const int wave = tid >> 6, lane = tid & 63;
    for (int si = 0; si < 4; ++si) {
        int s = wave * 4 + si;
        const float* u2p = u2 + ((size_t)b * Sseq + s) * Hdim;
        float sum = 0.f;
#pragma unroll
        for (int i = 0; i < 8; ++i) {
            int hh = lane + i * 64;
            sum += vS[hh] * tanhf(qpS[hh] + u2p[hh]);
        }
        for (int off = 32; off > 0; off >>= 1) sum += __shfl_down(sum, off);
        if (lane == 0) {
            float pen = step ? mask[b * Sseq + s] * 1e8f : 0.f;
            logitS[s] = 10.f * sum - pen;
        }
    }
    __syncthreads();

    if (tid == 0) {
        float mx = logitS[0];
        int am = 0;
        for (int s = 1; s < Sseq; ++s)
            if (logitS[s] > mx) { mx = logitS[s]; am = s; }
        float se = 0.f;
        for (int s = 0; s < Sseq; ++s) se += expf(logitS[s] - mx);
        float lp = -logf(se);
        float llv = (step ? ll_ws[b] : 0.f) + lp;
        ll_ws[b] = llv;
        out_ll[b] = llv;
        nxt[b] = am;
        if (step == 0) {
            for (int s = 0; s < Sseq; ++s) mask[b * Sseq + s] = (s == am) ? 1.f : 0.f;
        } else {
            mask[b * Sseq + am] += 1.f;
        }
        out_map[b * Sseq + am] = (float)node;
    }
}

// ---------------------------------------------------------------------------
extern "C" void kernel_launch(void* const* d_in, const int* in_sizes, int n_in,
                              void* d_out, int out_size, void* d_ws, size_t ws_size,
                              hipStream_t stream) {
    const float* x       = (const float*)d_in[0];
    const float* emb_W   = (const float*)d_in[1];
    const float* enc_Wih = (const float*)d_in[2];
    const float* enc_Whh = (const float*)d_in[3];
    const float* enc_b   = (const float*)d_in[4];
    const float* dec_Wih = (const float*)d_in[5];
    const float* dec_Whh = (const float*)d_in[6];
    const float* dec_b   = (const float*)d_in[7];
    const float* Wq2     = (const float*)d_in[8];
    const float* bq2     = (const float*)d_in[9];
    const float* Wref2   = (const float*)d_in[10];
    const float* bref2   = (const float*)d_in[11];
    const float* Vec2    = (const float*)d_in[12];
    const float* dec0    = (const float*)d_in[13];

    // workspace layout — ~195 MB
    float* ws      = (float*)d_ws;
    float* u2      = ws;                                   // B*S*H fp32
    float* h0      = u2 + (size_t)Bsz * Sseq * Hdim;       // B*H each
    float* c0      = h0 + (size_t)Bsz * Hdim;
    float* h1      = c0 + (size_t)Bsz * Hdim;
    float* c1      = h1 + (size_t)Bsz * Hdim;
    float* qp      = c1 + (size_t)Bsz * Hdim;
    float* mask    = qp + (size_t)Bsz * Hdim;              // B*S
    float* ll      = mask + (size_t)Bsz * Sseq;            // B
    int*   nxt     = (int*)(ll + Bsz);                     // B
    float* encBI   = (float*)(nxt + Bsz);                  // 2048 each
    float* decBI   = encBI + H4;
    float* v0bI    = decBI + H4;
    // bf16 weight planes (ushort)
    unsigned short* us = (unsigned short*)(v0bI + H4);
    unsigned short* encEh = us;                       us += (size_t)H4 * Gdim;
    unsigned short* encEm = us;                       us += (size_t)H4 * Gdim;
    unsigned short* encEl = us;                       us += (size_t)H4 * Gdim;
    unsigned short* encWh = us;                       us += (size_t)H4 * Hdim;
    unsigned short* encWm = us;                       us += (size_t)H4 * Hdim;
    unsigned short* encWl = us;                       us += (size_t)H4 * Hdim;
    unsigned short* decEh = us;                       us += (size_t)H4 * Gdim;
    unsigned short* decEm = us;                       us += (size_t)H4 * Gdim;
    unsigned short* decEl = us;                       us += (size_t)H4 * Gdim;
    unsigned short* decWh = us;                       us += (size_t)H4 * Hdim;
    unsigned short* decWm = us;                       us += (size_t)H4 * Hdim;
    unsigned short* decWl = us;                       us += (size_t)H4 * Hdim;
    // projection weight planes (512x512 each)
    unsigned short* prWh = us;                        us += (size_t)Hdim * Hdim;
    unsigned short* prWm = us;                        us += (size_t)Hdim * Hdim;
    unsigned short* prWl = us;                        us += (size_t)Hdim * Hdim;
    unsigned short* pqWh = us;                        us += (size_t)Hdim * Hdim;
    unsigned short* pqWm = us;                        us += (size_t)Hdim * Hdim;
    unsigned short* pqWl = us;                        us += (size_t)Hdim * Hdim;

    float* out_map = (float*)d_out;                        // B*P floats
    float* out_ll  = out_map + (size_t)Bsz * Psteps;       // B floats

    static const int nodes[Psteps] = {0,0,0,0, 1,1,1,1, 2,2,2,2, 3,3,3,3};

    fold_kernel<<<H4, Gdim, 0, stream>>>(enc_Wih, enc_Whh, enc_b,
                                         dec_Wih, dec_Whh, dec_b,
                                         emb_W, dec0,
                                         encEh, encEm, encEl, encWh, encWm, encWl,
                                         decEh, decEm, decEl, decWh, decWm, decWl,
                                         encBI, decBI, v0bI);
    fold_proj<<<dim3(Hdim, 2), 256, 0, stream>>>(Wref2, Wq2,
                                                 prWh, prWm, prWl,
                                                 pqWh, pqWm, pqWl);

    const dim3 gBig(32, 16);    // gates grid: 512 blocks (512 thr) = 2/CU
    const dim3 gPr(64, 8);      // proj grid:  512 blocks = 2/CU

    // ---- encoder: 16 fused LSTM steps + u2[t] projection of h(t) ----
    for (int t = 0; t < Sseq; ++t) {
        float* ho = (t & 1) ? h0 : h1;
        float* co = (t & 1) ? c0 : c1;
        const float* hi = (t & 1) ? h1 : h0;
        const float* ci = (t & 1) ? c1 : c0;
        if (t == 0) {
            gates_mfma<<<gBig, 512, 0, stream>>>(
                encEh, encEm, encEl, Gdim,
                x, Sseq * Gdim, nullptr, 0,
                nullptr, nullptr, nullptr, 0, nullptr,
                encBI, ci, ho, co, 1);
        } else {
            gates_mfma<<<gBig, 512, 0, stream>>>(
                encEh, encEm, encEl, Gdim,
                x + t * Gdim, Sseq * Gdim, nullptr, 0,
                encWh, encWm, encWl, Hdim, hi,
                encBI, ci, ho, co, 0);
        }
        proj_mfma<<<gPr, 256, 0, stream>>>(prWh, prWm, prWl, ho, bref2,
                                           u2 + (size_t)t * Hdim, Sseq * Hdim);
    }

    // ---- decoder: 16 autoregressive steps ----
    for (int p = 0; p < Psteps; ++p) {
        const int u = Sseq + p;
        float* ho = (u & 1) ? h0 : h1;
        float* co = (u & 1) ? c0 : c1;
        const float* hi = (u & 1) ? h1 : h0;
        const float* ci = (u & 1) ? c1 : c0;
        if (p == 0) {
            gates_mfma<<<gBig, 512, 0, stream>>>(
                nullptr, nullptr, nullptr, 0,
                nullptr, 0, nullptr, 0,
                decWh, decWm, decWl, Hdim, hi,
                v0bI, ci, ho, co, 0);
        } else {
            gates_mfma<<<gBig, 512, 0, stream>>>(
                decEh, decEm, decEl, Gdim,
                x, Sseq * Gdim, nxt, Gdim,
                decWh, decWm, decWl, Hdim, hi,
                decBI, ci, ho, co, 0);
        }
        proj_mfma<<<gPr, 256, 0, stream>>>(pqWh, pqWm, pqWl, ho, bq2,
                                           qp, Hdim);
        attn_step<<<Bsz, 256, 0, stream>>>(qp, u2, Vec2, mask, ll, nxt,
                                           out_map, out_ll, p, nodes[p]);
    }
}

// Round 15
// 3230.891 us; speedup vs baseline: 1.1873x; 1.0098x over previous
//
#include <hip/hip_runtime.h>
#include <cstddef>

// Problem constants
#define Bsz  4096
#define Sseq 16
#define Gdim 128
#define Edim 256
#define Hdim 512
#define H4   2048
#define Psteps 16
#define BK   16

typedef short bfrag8 __attribute__((ext_vector_type(8)));   // 8 bf16 (4 VGPR)
typedef float f32x4  __attribute__((ext_vector_type(4)));   // MFMA acc

// Exact 3-way bf16 split of fp32 (truncation; residuals exactly representable:
// 24 mantissa bits = 8+8+8). a == hi+mid+lo exactly (normal range).
__device__ __forceinline__ void split3(float f, unsigned short& h,
                                       unsigned short& m, unsigned short& l) {
    unsigned u = __float_as_uint(f);
    h = (unsigned short)(u >> 16);
    float r1 = f - __uint_as_float(u & 0xffff0000u);
    unsigned u1 = __float_as_uint(r1);
    m = (unsigned short)(u1 >> 16);
    float r2 = r1 - __uint_as_float(u1 & 0xffff0000u);
    l = (unsigned short)(__float_as_uint(r2) >> 16);
}

// ---------------------------------------------------------------------------
// Fold kernel: gate-interleaved (row c = j*4+gate) weight prep, emitting
// bf16 hi/mid/lo planes for the MFMA path. Wih rows staged in LDS first
// (coalesced), e-loop reads LDS broadcasts -- same sequential FMA order.
// ---------------------------------------------------------------------------
__global__ void fold_kernel(const float* __restrict__ encWih,
                            const float* __restrict__ encWhh,
                            const float* __restrict__ enc_b,
                            const float* __restrict__ decWih,
                            const float* __restrict__ decWhh,
                            const float* __restrict__ dec_b,
                            const float* __restrict__ embW,
                            const float* __restrict__ dec0,
                            unsigned short* __restrict__ encEh,
                            unsigned short* __restrict__ encEm,
                            unsigned short* __restrict__ encEl,
                            unsigned short* __restrict__ encWh,
                            unsigned short* __restrict__ encWm,
                            unsigned short* __restrict__ encWl,
                            unsigned short* __restrict__ decEh,
                            unsigned short* __restrict__ decEm,
                            unsigned short* __restrict__ decEl,
                            unsigned short* __restrict__ decWh,
                            unsigned short* __restrict__ decWm,
                            unsigned short* __restrict__ decWl,
                            float* __restrict__ encBI, float* __restrict__ decBI,
                            float* __restrict__ v0bI) {
    __shared__ float rE[Edim], rD[Edim];
    const int o = blockIdx.x;            // original row 0..2047 (gate*512 + j)
    const int gate = o >> 9, j = o & 511;
    const int c = j * 4 + gate;          // interleaved row
    const int g = threadIdx.x;           // 0..127
    rE[g]        = encWih[(size_t)o * Edim + g];
    rE[g + Gdim] = encWih[(size_t)o * Edim + g + Gdim];
    rD[g]        = decWih[(size_t)o * Edim + g];
    rD[g + Gdim] = decWih[(size_t)o * Edim + g + Gdim];
    __syncthreads();

    float se = 0.f, sd = 0.f;
#pragma unroll 8
    for (int e = 0; e < Edim; ++e) {
        float w = embW[e * Gdim + g];
        se += rE[e] * w;                 // same sequential order as before
        sd += rD[e] * w;
    }
    unsigned short h, m, l;
    split3(se, h, m, l);
    encEh[(size_t)c * Gdim + g] = h; encEm[(size_t)c * Gdim + g] = m;
    encEl[(size_t)c * Gdim + g] = l;
    split3(sd, h, m, l);
    decEh[(size_t)c * Gdim + g] = h; decEm[(size_t)c * Gdim + g] = m;
    decEl[(size_t)c * Gdim + g] = l;
    for (int k = g; k < Hdim; k += Gdim) {
        split3(encWhh[(size_t)o * Hdim + k], h, m, l);
        encWh[(size_t)c * Hdim + k] = h; encWm[(size_t)c * Hdim + k] = m;
        encWl[(size_t)c * Hdim + k] = l;
        split3(decWhh[(size_t)o * Hdim + k], h, m, l);
        decWh[(size_t)c * Hdim + k] = h; decWm[(size_t)c * Hdim + k] = m;
        decWl[(size_t)c * Hdim + k] = l;
    }
    if (g == 0) {
        encBI[c] = enc_b[o];
        decBI[c] = dec_b[o];
        float s = dec_b[o];
        for (int e = 0; e < Edim; ++e) s += rD[e] * dec0[e];  // same order
        v0bI[c] = s;
    }
}

// ---------------------------------------------------------------------------
// Plane prep for the projection weights (Wref2, Wq2): row-major hi/mid/lo
// bf16 planes, 512x512 each. grid (512, 2).
// ---------------------------------------------------------------------------
__global__ __launch_bounds__(256) void fold_proj(
    const float* __restrict__ Wr, const float* __restrict__ Wq,
    unsigned short* __restrict__ rWh, unsigned short* __restrict__ rWm,
    unsigned short* __restrict__ rWl,
    unsigned short* __restrict__ qWh, unsigned short* __restrict__ qWm,
    unsigned short* __restrict__ qWl) {
    const int o = blockIdx.x;
    const float* src = blockIdx.y ? Wq : Wr;
    unsigned short* ph = blockIdx.y ? qWh : rWh;
    unsigned short* pm = blockIdx.y ? qWm : rWm;
    unsigned short* pl = blockIdx.y ? qWl : rWl;
    for (int k = threadIdx.x; k < Hdim; k += 256) {
        unsigned short h, m, l;
        split3(src[(size_t)o * Hdim + k], h, m, l);
        ph[(size_t)o * Hdim + k] = h;
        pm[(size_t)o * Hdim + k] = m;
        pl[(size_t)o * Hdim + k] = l;
    }
}

// ---------------------------------------------------------------------------
// MFMA gates GEMM + fused LSTM epilogue, fp32-exact via bf16x6 emulation.
// Round-15: round-13 shell (128m x 128n block, 8 waves / 512 thr, wave =
// 16m x 128n, grid (32,16)=512, weight LDS double-buffer 48 KB) with the
// act-LDS staging REMOVED: in the 16m x 128n wave layout each wave's act
// rows are PRIVATE (zero cross-wave reuse), so staging them dedup'd nothing
// while costing 2 gload_lds/thread/chunk, the 655K-1.3M act ds_read bank
// conflicts, and 32 KB LDS that capped residency at 2 blocks/CU. Acts now
// load direct per-lane float4 (bit-identical values; h/x are L2/L3
// resident); LDS 48 KB -> 3 blocks/CU = 24 waves/CU = 6 waves/SIMD.
// (Round-12 tested direct acts but confounded it with halved blocks.)
// Weight staging, swizzles, chunk order, 6-MFMA order verbatim ->
// output bit-identical.
// ---------------------------------------------------------------------------
__global__ __launch_bounds__(512) void gates_mfma(
    const unsigned short* __restrict__ Wh1, const unsigned short* __restrict__ Wm1,
    const unsigned short* __restrict__ Wl1, int K1,
    const float* __restrict__ X, int ldx,
    const int* __restrict__ gather, int gmul,
    const unsigned short* __restrict__ Wh2, const unsigned short* __restrict__ Wm2,
    const unsigned short* __restrict__ Wl2, int K2,
    const float* __restrict__ Hin,
    const float* __restrict__ biasI,
    const float* __restrict__ c_in, float* __restrict__ h_out,
    float* __restrict__ c_out, int czero)
{
    __shared__ __align__(16) unsigned short wlds[2][3 * 4096]; // 48 KB

    const int tid = threadIdx.x;                 // 0..511
    const int wv = tid >> 6, lane = tid & 63;    // 8 waves
    const int lm = lane & 15, quad = lane >> 4;
    const int c0 = blockIdx.y * 128;             // block n-panel base row
    const int mB0 = blockIdx.x * 128;            // block batch base (128 rows)

    const int mrow = mB0 + wv * 16 + lm;         // this lane's act/output row

    // ---- weight staging: 128 rows x 4 units x 3 planes; 512 thr, 1 unit
    //      per thread per plane. Wave wv stages rows wv*16..wv*16+15.
    const int srow = wv * 16 + (lane >> 2);
    const int sqs = (lane & 3) ^ ((srow >> 1) & 3);   // pre-swizzled src unit
    const size_t roff1 = (size_t)(c0 + srow) * K1 + (size_t)(sqs * 8);
    const size_t roff2 = (size_t)(c0 + srow) * K2 + (size_t)(sqs * 8);

    // ---- act pointers (direct global; wave rows are private, no dup) ----
    const float* xr = nullptr;
    const float* hr = nullptr;
    if (X) {
        size_t off = (size_t)mrow * ldx;
        if (gather) off += (size_t)gather[mrow] * gmul;
        xr = X + off;
    }
    if (Hin) hr = Hin + (size_t)mrow * K2;

    // ---- weight ds_read fragment offsets (ushort units), 8 n-tiles ----
    int boffW[8];
#pragma unroll
    for (int tn = 0; tn < 8; ++tn) {
        const int r = tn * 16 + lm;
        boffW[tn] = r * 32 + ((quad ^ ((r >> 1) & 3)) * 8);
    }

    auto stage = [&](int kcN, int buf) {
        const bool nX = kcN < K1;
        const int kb = nX ? kcN : kcN - K1;
        unsigned short* lb = &wlds[buf][wv * 512];
        const unsigned short* gh = (nX ? Wh1 + roff1 : Wh2 + roff2) + kb;
        const unsigned short* gm = (nX ? Wm1 + roff1 : Wm2 + roff2) + kb;
        const unsigned short* gl = (nX ? Wl1 + roff1 : Wl2 + roff2) + kb;
        __builtin_amdgcn_global_load_lds(
            (const __attribute__((address_space(1))) void*)gh,
            (__attribute__((address_space(3))) void*)(lb), 16, 0, 0);
        __builtin_amdgcn_global_load_lds(
            (const __attribute__((address_space(1))) void*)gm,
            (__attribute__((address_space(3))) void*)(lb + 4096), 16, 0, 0);
        __builtin_amdgcn_global_load_lds(
            (const __attribute__((address_space(1))) void*)gl,
            (__attribute__((address_space(3))) void*)(lb + 8192), 16, 0, 0);
    };

    f32x4 acc[8];
#pragma unroll
    for (int i = 0; i < 8; ++i) acc[i] = (f32x4){0.f, 0.f, 0.f, 0.f};

    const int KT = K1 + K2;
    stage(0, 0);
    int cur = 0;

    for (int kc = 0; kc < KT; kc += 32) {
        __syncthreads();                       // drains staged loads for buf[cur]
        if (kc + 32 < KT) stage(kc + 32, cur ^ 1);

        const bool inX = kc < K1;
        const int kk = (inX ? kc : kc - K1) + quad * 8;

        // this wave's single act fragment: direct global, split3 in VALU
        const float* p = (inX ? xr : hr) + kk;
        float a8[8];
        *(float4*)&a8[0] = *(const float4*)(p);
        *(float4*)&a8[4] = *(const float4*)(p + 4);
        bfrag8 bh, bm, bl;
#pragma unroll
        for (int j = 0; j < 8; ++j) {
            unsigned short h, m, l;
            split3(a8[j], h, m, l);
            bh[j] = (short)h; bm[j] = (short)m; bl[j] = (short)l;
        }

        const unsigned short* bufp = wlds[cur];
#pragma unroll
        for (int hh = 0; hh < 2; ++hh) {
            bfrag8 ah[4], am4[4], al[4];
#pragma unroll
            for (int t = 0; t < 4; ++t) {
                const int tn = hh * 4 + t;
                ah[t]  = *(const bfrag8*)(bufp + boffW[tn]);
                am4[t] = *(const bfrag8*)(bufp + 4096 + boffW[tn]);
                al[t]  = *(const bfrag8*)(bufp + 8192 + boffW[tn]);
            }
#pragma unroll
            for (int t = 0; t < 4; ++t) {
                const int tn = hh * 4 + t;
                f32x4 c = acc[tn];
                c = __builtin_amdgcn_mfma_f32_16x16x32_bf16(ah[t], bl, c, 0, 0, 0);
                c = __builtin_amdgcn_mfma_f32_16x16x32_bf16(al[t], bh, c, 0, 0, 0);
                c = __builtin_amdgcn_mfma_f32_16x16x32_bf16(am4[t], bm, c, 0, 0, 0);
                c = __builtin_amdgcn_mfma_f32_16x16x32_bf16(ah[t], bm, c, 0, 0, 0);
                c = __builtin_amdgcn_mfma_f32_16x16x32_bf16(am4[t], bh, c, 0, 0, 0);
                c = __builtin_amdgcn_mfma_f32_16x16x32_bf16(ah[t], bh, c, 0, 0, 0);
                acc[tn] = c;
            }
        }
        cur ^= 1;
    }

    // fused LSTM epilogue: lane's 4 acc regs = gates i,f,g,o of unit j
#pragma unroll
    for (int tn = 0; tn < 8; ++tn) {
        const int nb = c0 + tn * 16 + quad * 4;
        float4 bb = *(const float4*)(biasI + nb);
        const int j = nb >> 2;
        const size_t idx = (size_t)mrow * Hdim + j;
        float gi = acc[tn][0] + bb.x;
        float gf = acc[tn][1] + bb.y;
        float gg = acc[tn][2] + bb.z;
        float go = acc[tn][3] + bb.w;
        float si = 1.f / (1.f + expf(-gi));
        float sf = 1.f / (1.f + expf(-gf));
        float so = 1.f / (1.f + expf(-go));
        float co = czero ? 0.f : c_in[idx];
        float cn = si * tanhf(gg) + sf * co;
        c_out[idx] = cn;
        h_out[idx] = so * tanhf(cn);
    }
}

// ---------------------------------------------------------------------------
// MFMA projection GEMM: C = A @ W^T + bias (A 4096x512 fp32, W via bf16x6
// planes, K=512). Same bf16x6 scheme as gates (identical 6-term order).
// 64m x 64n block, 4 waves (wave = 16m x 64n, acc 4x1), grid (64,8)=512,
// dual LDS double-buffer staging with the proven both-sides swizzles.
// (round-11 version, verbatim)
// ---------------------------------------------------------------------------
__global__ __launch_bounds__(256) void proj_mfma(
    const unsigned short* __restrict__ Wh, const unsigned short* __restrict__ Wm,
    const unsigned short* __restrict__ Wl,
    const float* __restrict__ A,
    const float* __restrict__ bias,
    float* __restrict__ C, int ldc)
{
    __shared__ __align__(16) unsigned short wlds[2][3 * 2048]; // 24 KB
    __shared__ __align__(16) float alds[2][64 * 32];           // 16 KB

    const int tid = threadIdx.x;
    const int wv = tid >> 6, lane = tid & 63;
    const int lm = lane & 15, quad = lane >> 4;
    const int nB0 = blockIdx.y * 64;             // output-channel panel base
    const int mB0 = blockIdx.x * 64;             // batch tile base

    // ---- weight staging: 64 rows x 4 x 16B units, 256 threads, 1 issue ----
    const int rw = tid >> 2;                               // row 0..63
    const int sqw = (tid & 3) ^ ((rw >> 1) & 3);           // swizzled src unit
    const size_t wroff = (size_t)(nB0 + rw) * Hdim + (size_t)(sqw * 8);

    // ---- act staging: 2 issues x 32 rows x 8 x 16B units ----
    const int asw = ((lane & 7) ^ (lane >> 3)) * 4;        // swizzled src floats
    const float* asrc[2];
#pragma unroll
    for (int i = 0; i < 2; ++i) {
        const int r = i * 32 + wv * 8 + (lane >> 3);
        asrc[i] = A + (size_t)(mB0 + r) * Hdim + asw;
    }

    // ---- ds_read offsets ----
    int boffW[4];
#pragma unroll
    for (int tn = 0; tn < 4; ++tn) {
        const int r = tn * 16 + lm;
        boffW[tn] = r * 32 + ((quad ^ ((r >> 1) & 3)) * 8);
    }
    const int ra = wv * 16 + lm;                           // wave's act row
    const int boffA1 = ra * 32 + (((2 * quad)     ^ (lm & 7)) << 2);
    const int boffA2 = ra * 32 + (((2 * quad + 1) ^ (lm & 7)) << 2);

    auto stage = [&](int kb, int buf) {
        unsigned short* lb0 = &wlds[buf][wv * 512];
        __builtin_amdgcn_global_load_lds(
            (const __attribute__((address_space(1))) void*)(Wh + wroff + kb),
            (__attribute__((address_space(3))) void*)(lb0), 16, 0, 0);
        __builtin_amdgcn_global_load_lds(
            (const __attribute__((address_space(1))) void*)(Wm + wroff + kb),
            (__attribute__((address_space(3))) void*)(lb0 + 2048), 16, 0, 0);
        __builtin_amdgcn_global_load_lds(
            (const __attribute__((address_space(1))) void*)(Wl + wroff + kb),
            (__attribute__((address_space(3))) void*)(lb0 + 4096), 16, 0, 0);
#pragma unroll
        for (int i = 0; i < 2; ++i) {
            float* lb = &alds[buf][(i * 32 + wv * 8) * 32];
            __builtin_amdgcn_global_load_lds(
                (const __attribute__((address_space(1))) void*)(asrc[i] + kb),
                (__attribute__((address_space(3))) void*)lb, 16, 0, 0);
        }
    };

    f32x4 acc[4];
#pragma unroll
    for (int i = 0; i < 4; ++i) acc[i] = (f32x4){0.f, 0.f, 0.f, 0.f};

    stage(0, 0);
    int cur = 0;

    for (int kc = 0; kc < Hdim; kc += 32) {
        __syncthreads();
        if (kc + 32 < Hdim) stage(kc + 32, cur ^ 1);

        const float* abuf = alds[cur];
        float a8[8];
        *(float4*)&a8[0] = *(const float4*)(abuf + boffA1);
        *(float4*)&a8[4] = *(const float4*)(abuf + boffA2);
        bfrag8 bh, bm, bl;
#pragma unroll
        for (int j = 0; j < 8; ++j) {
            unsigned short h, m, l;
            split3(a8[j], h, m, l);
            bh[j] = (short)h; bm[j] = (short)m; bl[j] = (short)l;
        }

        const unsigned short* bufp = wlds[cur];
#pragma unroll
        for (int tn = 0; tn < 4; ++tn) {
            bfrag8 ah  = *(const bfrag8*)(bufp + boffW[tn]);
            bfrag8 am4 = *(const bfrag8*)(bufp + 2048 + boffW[tn]);
            bfrag8 al  = *(const bfrag8*)(bufp + 4096 + boffW[tn]);
            f32x4 c = acc[tn];
            c = __builtin_amdgcn_mfma_f32_16x16x32_bf16(ah,  bl, c, 0, 0, 0);
            c = __builtin_amdgcn_mfma_f32_16x16x32_bf16(al,  bh, c, 0, 0, 0);
            c = __builtin_amdgcn_mfma_f32_16x16x32_bf16(am4, bm, c, 0, 0, 0);
            c = __builtin_amdgcn_mfma_f32_16x16x32_bf16(ah,  bm, c, 0, 0, 0);
            c = __builtin_amdgcn_mfma_f32_16x16x32_bf16(am4, bh, c, 0, 0, 0);
            c = __builtin_amdgcn_mfma_f32_16x16x32_bf16(ah,  bh, c, 0, 0, 0);
            acc[tn] = c;
        }
        cur ^= 1;
    }

    // epilogue: lane reg r of acc[tn] = channel nB0+tn*16+quad*4+r, batch
    // row mB0+wv*16+lm (planes NOT gate-interleaved).
    const int m = mB0 + wv * 16 + lm;
#pragma unroll
    for (int tn = 0; tn < 4; ++tn) {
        const int n = nB0 + tn * 16 + quad * 4;
        float4 bb = *(const float4*)(bias + n);
        float4 o;
        o.x = acc[tn][0] + bb.x;
        o.y = acc[tn][1] + bb.y;
        o.z = acc[tn][2] + bb.z;
        o.w = acc[tn][3] + bb.w;
        *(float4*)(C + (size_t)m * ldc + n) = o;
    }
}

// ---------------------------------------------------------------------------
// Attention + log-softmax + argmax + state update.
// ---------------------------------------------------------------------------
__global__ __launch_bounds__(256) void attn_step(const float* __restrict__ qp,
                                                 const float* __restrict__ u2,
                                                 const float* __restrict__ Vec2,
                                                 float* __restrict__ mask,
                                                 float* __restrict__ ll_ws,
                                                 int* __restrict__ nxt,
                                                 float* __restrict__ out_map,
                                                 float* __restrict__ out_ll,
                                                 int step, int node) {
    const int b = blockIdx.x;
    __shared__ float qpS[Hdim];
    __shared__ float vS[Hdim];
    __shared__ float logitS[Sseq];
    const int tid = threadIdx.x;
    qpS[tid]       = qp[(size_t)b * Hdim + tid];
    qpS[tid + 256] = qp[(size_t)b * Hdim + 256 + tid];
    vS[tid]        = Vec2[tid];
    vS[tid + 256]  = Vec2[256 + tid];
    __syncthreads();

    const int wave = tid >> 6, lane = tid & 63;
    for (int si = 0; si < 4; ++si) {
        int s = wave * 4 + si;
        const float* u2p = u2 + ((size_t)b * Sseq + s) * Hdim;
        float sum = 0.f;
#pragma unroll
        for (int i = 0; i < 8; ++i) {
            int hh = lane + i * 64;
            sum += vS[hh] * tanhf(qpS[hh] + u2p[hh]);
        }
        for (int off = 32; off > 0; off >>= 1) sum += __shfl_down(sum, off);
        if (lane == 0) {
            float pen = step ? mask[b * Sseq + s] * 1e8f : 0.f;
            logitS[s] = 10.f * sum - pen;
        }
    }
    __syncthreads();

    if (tid == 0) {
        float mx = logitS[0];
        int am = 0;
        for (int s = 1; s < Sseq; ++s)
            if (logitS[s] > mx) { mx = logitS[s]; am = s; }
        float se = 0.f;
        for (int s = 0; s < Sseq; ++s) se += expf(logitS[s] - mx);
        float lp = -logf(se);
        float llv = (step ? ll_ws[b] : 0.f) + lp;
        ll_ws[b] = llv;
        out_ll[b] = llv;
        nxt[b] = am;
        if (step == 0) {
            for (int s = 0; s < Sseq; ++s) mask[b * Sseq + s] = (s == am) ? 1.f : 0.f;
        } else {
            mask[b * Sseq + am] += 1.f;
        }
        out_map[b * Sseq + am] = (float)node;
    }
}

// ---------------------------------------------------------------------------
extern "C" void kernel_launch(void* const* d_in, const int* in_sizes, int n_in,
                              void* d_out, int out_size, void* d_ws, size_t ws_size,
                              hipStream_t stream) {
    const float* x       = (const float*)d_in[0];
    const float* emb_W   = (const float*)d_in[1];
    const float* enc_Wih = (const float*)d_in[2];
    const float* enc_Whh = (const float*)d_in[3];
    const float* enc_b   = (const float*)d_in[4];
    const float* dec_Wih = (const float*)d_in[5];
    const float* dec_Whh = (const float*)d_in[6];
    const float* dec_b   = (const float*)d_in[7];
    const float* Wq2     = (const float*)d_in[8];
    const float* bq2     = (const float*)d_in[9];
    const float* Wref2   = (const float*)d_in[10];
    const float* bref2   = (const float*)d_in[11];
    const float* Vec2    = (const float*)d_in[12];
    const float* dec0    = (const float*)d_in[13];

    // workspace layout — ~195 MB
    float* ws      = (float*)d_ws;
    float* u2      = ws;                                   // B*S*H fp32
    float* h0      = u2 + (size_t)Bsz * Sseq * Hdim;       // B*H each
    float* c0      = h0 + (size_t)Bsz * Hdim;
    float* h1      = c0 + (size_t)Bsz * Hdim;
    float* c1      = h1 + (size_t)Bsz * Hdim;
    float* qp      = c1 + (size_t)Bsz * Hdim;
    float* mask    = qp + (size_t)Bsz * Hdim;              // B*S
    float* ll      = mask + (size_t)Bsz * Sseq;            // B
    int*   nxt     = (int*)(ll + Bsz);                     // B
    float* encBI   = (float*)(nxt + Bsz);                  // 2048 each
    float* decBI   = encBI + H4;
    float* v0bI    = decBI + H4;
    // bf16 weight planes (ushort)
    unsigned short* us = (unsigned short*)(v0bI + H4);
    unsigned short* encEh = us;                       us += (size_t)H4 * Gdim;
    unsigned short* encEm = us;                       us += (size_t)H4 * Gdim;
    unsigned short* encEl = us;                       us += (size_t)H4 * Gdim;
    unsigned short* encWh = us;                       us += (size_t)H4 * Hdim;
    unsigned short* encWm = us;                       us += (size_t)H4 * Hdim;
    unsigned short* encWl = us;                       us += (size_t)H4 * Hdim;
    unsigned short* decEh = us;                       us += (size_t)H4 * Gdim;
    unsigned short* decEm = us;                       us += (size_t)H4 * Gdim;
    unsigned short* decEl = us;                       us += (size_t)H4 * Gdim;
    unsigned short* decWh = us;                       us += (size_t)H4 * Hdim;
    unsigned short* decWm = us;                       us += (size_t)H4 * Hdim;
    unsigned short* decWl = us;                       us += (size_t)H4 * Hdim;
    // projection weight planes (512x512 each)
    unsigned short* prWh = us;                        us += (size_t)Hdim * Hdim;
    unsigned short* prWm = us;                        us += (size_t)Hdim * Hdim;
    unsigned short* prWl = us;                        us += (size_t)Hdim * Hdim;
    unsigned short* pqWh = us;                        us += (size_t)Hdim * Hdim;
    unsigned short* pqWm = us;                        us += (size_t)Hdim * Hdim;
    unsigned short* pqWl = us;                        us += (size_t)Hdim * Hdim;

    float* out_map = (float*)d_out;                        // B*P floats
    float* out_ll  = out_map + (size_t)Bsz * Psteps;       // B floats

    static const int nodes[Psteps] = {0,0,0,0, 1,1,1,1, 2,2,2,2, 3,3,3,3};

    fold_kernel<<<H4, Gdim, 0, stream>>>(enc_Wih, enc_Whh, enc_b,
                                         dec_Wih, dec_Whh, dec_b,
                                         emb_W, dec0,
                                         encEh, encEm, encEl, encWh, encWm, encWl,
                                         decEh, decEm, decEl, decWh, decWm, decWl,
                                         encBI, decBI, v0bI);
    fold_proj<<<dim3(Hdim, 2), 256, 0, stream>>>(Wref2, Wq2,
                                                 prWh, prWm, prWl,
                                                 pqWh, pqWm, pqWl);

    const dim3 gBig(32, 16);    // gates grid: 512 blocks (512 thr), 48KB LDS
    const dim3 gPr(64, 8);      // proj grid:  512 blocks = 2/CU

    // ---- encoder: 16 fused LSTM steps + u2[t] projection of h(t) ----
    for (int t = 0; t < Sseq; ++t) {
        float* ho = (t & 1) ? h0 : h1;
        float* co = (t & 1) ? c0 : c1;
        const float* hi = (t & 1) ? h1 : h0;
        const float* ci = (t & 1) ? c1 : c0;
        if (t == 0) {
            gates_mfma<<<gBig, 512, 0, stream>>>(
                encEh, encEm, encEl, Gdim,
                x, Sseq * Gdim, nullptr, 0,
                nullptr, nullptr, nullptr, 0, nullptr,
                encBI, ci, ho, co, 1);
        } else {
            gates_mfma<<<gBig, 512, 0, stream>>>(
                encEh, encEm, encEl, Gdim,
                x + t * Gdim, Sseq * Gdim, nullptr, 0,
                encWh, encWm, encWl, Hdim, hi,
                encBI, ci, ho, co, 0);
        }
        proj_mfma<<<gPr, 256, 0, stream>>>(prWh, prWm, prWl, ho, bref2,
                                           u2 + (size_t)t * Hdim, Sseq * Hdim);
    }

    // ---- decoder: 16 autoregressive steps ----
    for (int p = 0; p < Psteps; ++p) {
        const int u = Sseq + p;
        float* ho = (u & 1) ? h0 : h1;
        float* co = (u & 1) ? c0 : c1;
        const float* hi = (u & 1) ? h1 : h0;
        const float* ci = (u & 1) ? c1 : c0;
        if (p == 0) {
            gates_mfma<<<gBig, 512, 0, stream>>>(
                nullptr, nullptr, nullptr, 0,
                nullptr, 0, nullptr, 0,
                decWh, decWm, decWl, Hdim, hi,
                v0bI, ci, ho, co, 0);
        } else {
            gates_mfma<<<gBig, 512, 0, stream>>>(
                decEh, decEm, decEl, Gdim,
                x, Sseq * Gdim, nxt, Gdim,
                decWh, decWm, decWl, Hdim, hi,
                decBI, ci, ho, co, 0);
        }
        proj_mfma<<<gPr, 256, 0, stream>>>(pqWh, pqWm, pqWl, ho, bq2,
                                           qp, Hdim);
        attn_step<<<Bsz, 256, 0, stream>>>(qp, u2, Vec2, mask, ll, nxt,
                                           out_map, out_ll, p, nodes[p]);
    }
}